// Round 2
// baseline (2548.023 us; speedup 1.0000x reference)
//
#include <hip/hip_runtime.h>

// LinearPerformerAttention on MI355X — round 2: fp32 baseline, small-footprint.
// B=4, N=4096, DIM=1024, H=16, HD=64, FEAT=256.
// Per-batch: kv-GEMM -> fused proj/elu/kv-state. Then fused q-gemm/proj/elu/attn/z,
// then out GEMM. Workspace: 117.5 MB (kvbuf 33.5 + attn 67 + kv 16.8 + ksum 0.07).

#define NTOK 4096
#define NB 4
#define ROWS 16384
#define DIM 1024
#define H3 3072
#define FEAT 256

// workspace float offsets
#define OFF_KVBUF 0u
#define OFF_ATTN  8388608u     // 4096*2048
#define OFF_KV    25165824u    // OFF_ATTN + 16384*1024
#define OFF_KSUM  29360128u    // OFF_KV + 64*256*64
#define WS_FLOATS 29376512u    // OFF_KSUM + 64*256
#define ZERO_F4   1052672u     // (kv + ksum) / 4

__device__ __forceinline__ float elu1f(float v) {
    return v > 0.f ? v + 1.f : __expf(v);
}

__global__ void zero_kernel(float4* p, unsigned n4) {
    for (unsigned i = blockIdx.x * blockDim.x + threadIdx.x; i < n4;
         i += gridDim.x * blockDim.x)
        p[i] = make_float4(0.f, 0.f, 0.f, 0.f);
}

// ---------------------------------------------------------------------------
// fp32 GEMM: C = A(MxK,lda) @ B(KxNc,ldb) [+bias], 128x128 tile, BK=16,
// 256 threads, 8x8 micro-tile. M,Nc mult of 128; K mult of 16.
// ---------------------------------------------------------------------------
__global__ __launch_bounds__(256) void sgemm_kernel(
    const float* __restrict__ A, const float* __restrict__ Bm,
    const float* __restrict__ bias, float* __restrict__ C,
    int M, int Nc, int K, int lda, int ldb, int ldc, int hasBias)
{
    __shared__ float As[16][128];   // transposed: As[k][m]
    __shared__ float Bs[16][128];
    const int tid = threadIdx.x;
    const int tx = tid & 15, ty = tid >> 4;
    const int col0 = blockIdx.x * 128;
    const int row0 = blockIdx.y * 128;

    float acc[8][8] = {};

    for (int k0 = 0; k0 < K; k0 += 16) {
        #pragma unroll
        for (int l = 0; l < 2; ++l) {
            int f  = tid + l * 256;
            int r  = f >> 2, c4 = f & 3;
            float4 v = *(const float4*)&A[(size_t)(row0 + r) * lda + k0 + c4 * 4];
            As[c4 * 4 + 0][r] = v.x;
            As[c4 * 4 + 1][r] = v.y;
            As[c4 * 4 + 2][r] = v.z;
            As[c4 * 4 + 3][r] = v.w;
        }
        #pragma unroll
        for (int l = 0; l < 2; ++l) {
            int f  = tid + l * 256;
            int rb = f >> 5, cb = f & 31;
            *(float4*)&Bs[rb][cb * 4] =
                *(const float4*)&Bm[(size_t)(k0 + rb) * ldb + col0 + cb * 4];
        }
        __syncthreads();
        #pragma unroll
        for (int k = 0; k < 16; ++k) {
            float a[8], b[8];
            *(float4*)&a[0] = *(const float4*)&As[k][ty * 8];
            *(float4*)&a[4] = *(const float4*)&As[k][ty * 8 + 4];
            *(float4*)&b[0] = *(const float4*)&Bs[k][tx * 8];
            *(float4*)&b[4] = *(const float4*)&Bs[k][tx * 8 + 4];
            #pragma unroll
            for (int i = 0; i < 8; ++i)
                #pragma unroll
                for (int j = 0; j < 8; ++j)
                    acc[i][j] += a[i] * b[j];
        }
        __syncthreads();
    }

    #pragma unroll
    for (int i = 0; i < 8; ++i) {
        size_t r = (size_t)(row0 + ty * 8 + i);
        #pragma unroll
        for (int jj = 0; jj < 2; ++jj) {
            int c = col0 + tx * 8 + jj * 4;
            float4 v;
            v.x = acc[i][jj * 4 + 0];
            v.y = acc[i][jj * 4 + 1];
            v.z = acc[i][jj * 4 + 2];
            v.w = acc[i][jj * 4 + 3];
            if (hasBias) {
                v.x += bias[c + 0]; v.y += bias[c + 1];
                v.z += bias[c + 2]; v.w += bias[c + 3];
            }
            *(float4*)&C[r * ldc + c] = v;
        }
    }
}

// ---------------------------------------------------------------------------
// Kernel 2: per (n-split, f-chunk, h) of batch b: kp = elu1(K @ projc),
// kv_chunk += kp^T V, ksum += colsum(kp). 64x64 kv chunk in regs, atomics.
// kvbuf rows are 2048 wide: k = cols 0..1023, v = cols 1024..2047.
// grid: (8, 4, 16); block 256.
// ---------------------------------------------------------------------------
__global__ __launch_bounds__(256) void kv_kernel(
    const float* __restrict__ kvbuf, const float* __restrict__ proj,
    float* __restrict__ kv, float* __restrict__ ksum, int b)
{
    __shared__ float Kl[64][68];   // staged K rows; reused to hold kp
    __shared__ float Vl[64][64];
    __shared__ float Pl[64][64];   // proj chunk [kk][f]
    const int tid = threadIdx.x;
    const int tx = tid & 15, ty = tid >> 4;
    const int ns = blockIdx.x, fc = blockIdx.y, h = blockIdx.z;
    const int bh = b * 16 + h;
    const int f0 = fc * 64;

    #pragma unroll
    for (int l = 0; l < 4; ++l) {
        int f4 = tid + l * 256;
        int kk = f4 >> 4, c4 = f4 & 15;
        *(float4*)&Pl[kk][c4 * 4] =
            *(const float4*)&proj[(size_t)(h * 64 + kk) * 256 + f0 + c4 * 4];
    }
    const float* kbase = kvbuf + h * 64;
    const float* vbase = kvbuf + 1024 + h * 64;

    float kvacc[4][4] = {};
    float ksacc[4] = {};
    __syncthreads();

    for (int t = 0; t < 8; ++t) {
        const int n0 = ns * 512 + t * 64;
        #pragma unroll
        for (int l = 0; l < 4; ++l) {
            int f4 = tid + l * 256;
            int r = f4 >> 4, c4 = f4 & 15;
            *(float4*)&Kl[r][c4 * 4] = *(const float4*)&kbase[(size_t)(n0 + r) * 2048 + c4 * 4];
            *(float4*)&Vl[r][c4 * 4] = *(const float4*)&vbase[(size_t)(n0 + r) * 2048 + c4 * 4];
        }
        __syncthreads();

        // kp[r=4ty+i][f=4tx+j] = elu1( sum_kk K[r][kk] * projc[kk][f] )
        float kp[4][4] = {};
        #pragma unroll
        for (int kk0 = 0; kk0 < 64; kk0 += 4) {
            float a[4][4], bb[4][4];
            #pragma unroll
            for (int i = 0; i < 4; ++i)
                *(float4*)&a[i][0] = *(const float4*)&Kl[ty * 4 + i][kk0];
            #pragma unroll
            for (int kx = 0; kx < 4; ++kx)
                *(float4*)&bb[kx][0] = *(const float4*)&Pl[kk0 + kx][tx * 4];
            #pragma unroll
            for (int i = 0; i < 4; ++i)
                #pragma unroll
                for (int kx = 0; kx < 4; ++kx) {
                    float av = a[i][kx];
                    #pragma unroll
                    for (int j = 0; j < 4; ++j) kp[i][j] += av * bb[kx][j];
                }
        }
        #pragma unroll
        for (int i = 0; i < 4; ++i)
            #pragma unroll
            for (int j = 0; j < 4; ++j) kp[i][j] = elu1f(kp[i][j]);

        __syncthreads();   // Kl reads done; safe to overwrite with kp
        #pragma unroll
        for (int i = 0; i < 4; ++i) {
            float4 v; v.x = kp[i][0]; v.y = kp[i][1]; v.z = kp[i][2]; v.w = kp[i][3];
            *(float4*)&Kl[ty * 4 + i][tx * 4] = v;
        }
        __syncthreads();

        // kv[f=4ty+i][d=4tx+j] += sum_nn kp[nn][f] * V[nn][d]
        #pragma unroll
        for (int nn = 0; nn < 64; ++nn) {
            float a[4], bv[4];
            *(float4*)&a[0]  = *(const float4*)&Kl[nn][ty * 4];
            *(float4*)&bv[0] = *(const float4*)&Vl[nn][tx * 4];
            #pragma unroll
            for (int i = 0; i < 4; ++i) ksacc[i] += a[i];
            #pragma unroll
            for (int i = 0; i < 4; ++i)
                #pragma unroll
                for (int j = 0; j < 4; ++j) kvacc[i][j] += a[i] * bv[j];
        }
        __syncthreads();
    }

    float* kvdst = kv + ((size_t)bh * 256 + f0) * 64;
    #pragma unroll
    for (int i = 0; i < 4; ++i)
        #pragma unroll
        for (int j = 0; j < 4; ++j)
            atomicAdd(&kvdst[(size_t)(ty * 4 + i) * 64 + tx * 4 + j], kvacc[i][j]);
    if (tx == 0) {
        #pragma unroll
        for (int i = 0; i < 4; ++i)
            atomicAdd(&ksum[(size_t)bh * 256 + f0 + ty * 4 + i], ksacc[i]);
    }
}

// ---------------------------------------------------------------------------
// Kernel 3: per (n-tile, bh): q_tile = x_tile @ Wq_h (on the fly, K=1024),
// then per f-chunk: qp = elu1(q @ projc), attn += qp @ kv_chunk,
// z = 1/(sum qp*ksum + 1e-8). Writes attn*z head-interleaved (ROWS x DIM).
// grid: (64, 64); block 256.
// ---------------------------------------------------------------------------
__global__ __launch_bounds__(256) void attn_kernel(
    const float* __restrict__ x, const float* __restrict__ w_qkv,
    const float* __restrict__ proj, const float* __restrict__ kv,
    const float* __restrict__ ksum, float* __restrict__ attn)
{
    __shared__ float Ql[64][68];   // q tile (rows x hd)
    __shared__ float Sb[64][64];   // time-shared: Xl chunk -> proj chunk -> kv chunk
    __shared__ float QP[64][68];   // time-shared: Wq chunk -> qp chunk
    __shared__ float ks[256];
    const int tid = threadIdx.x;
    const int tx = tid & 15, ty = tid >> 4;
    const int nt = blockIdx.x, bh = blockIdx.y;
    const int b = bh >> 4, h = bh & 15;
    const int n0 = nt * 64;

    ks[tid] = ksum[(size_t)bh * 256 + tid];

    // ---- phase 0: q_tile = x_tile(64x1024) @ w_qkv[:, h*64 .. h*64+63] ----
    float qacc[4][4] = {};
    for (int kk0 = 0; kk0 < 1024; kk0 += 64) {
        __syncthreads();
        #pragma unroll
        for (int l = 0; l < 4; ++l) {
            int f4 = tid + l * 256;
            int r = f4 >> 4, c4 = f4 & 15;
            *(float4*)&Sb[r][c4 * 4] =
                *(const float4*)&x[(size_t)(b * NTOK + n0 + r) * DIM + kk0 + c4 * 4];
            *(float4*)&QP[r][c4 * 4] =
                *(const float4*)&w_qkv[(size_t)(kk0 + r) * H3 + h * 64 + c4 * 4];
        }
        __syncthreads();
        #pragma unroll
        for (int kx0 = 0; kx0 < 64; kx0 += 4) {
            float a[4][4], bb[4][4];
            #pragma unroll
            for (int i = 0; i < 4; ++i)
                *(float4*)&a[i][0] = *(const float4*)&Sb[ty * 4 + i][kx0];
            #pragma unroll
            for (int kx = 0; kx < 4; ++kx)
                *(float4*)&bb[kx][0] = *(const float4*)&QP[kx0 + kx][tx * 4];
            #pragma unroll
            for (int i = 0; i < 4; ++i)
                #pragma unroll
                for (int kx = 0; kx < 4; ++kx) {
                    float av = a[i][kx];
                    #pragma unroll
                    for (int j = 0; j < 4; ++j) qacc[i][j] += av * bb[kx][j];
                }
        }
    }
    __syncthreads();
    #pragma unroll
    for (int i = 0; i < 4; ++i) {
        float4 v; v.x = qacc[i][0]; v.y = qacc[i][1]; v.z = qacc[i][2]; v.w = qacc[i][3];
        *(float4*)&Ql[ty * 4 + i][tx * 4] = v;
    }

    // ---- phase 1: f-chunk loop ----
    float attnacc[4][4] = {};
    float zacc[4] = {};

    for (int fc = 0; fc < 4; ++fc) {
        const int f0 = fc * 64;
        __syncthreads();   // Sb/QP free; Ql ready (fc==0) or prev accum done
        #pragma unroll
        for (int l = 0; l < 4; ++l) {
            int f4 = tid + l * 256;
            int kk = f4 >> 4, c4 = f4 & 15;
            *(float4*)&Sb[kk][c4 * 4] =
                *(const float4*)&proj[(size_t)(h * 64 + kk) * 256 + f0 + c4 * 4];
        }
        __syncthreads();

        float qp[4][4] = {};
        #pragma unroll
        for (int kk0 = 0; kk0 < 64; kk0 += 4) {
            float a[4][4], bb[4][4];
            #pragma unroll
            for (int i = 0; i < 4; ++i)
                *(float4*)&a[i][0] = *(const float4*)&Ql[ty * 4 + i][kk0];
            #pragma unroll
            for (int kx = 0; kx < 4; ++kx)
                *(float4*)&bb[kx][0] = *(const float4*)&Sb[kk0 + kx][tx * 4];
            #pragma unroll
            for (int i = 0; i < 4; ++i)
                #pragma unroll
                for (int kx = 0; kx < 4; ++kx) {
                    float av = a[i][kx];
                    #pragma unroll
                    for (int j = 0; j < 4; ++j) qp[i][j] += av * bb[kx][j];
                }
        }
        #pragma unroll
        for (int i = 0; i < 4; ++i)
            #pragma unroll
            for (int j = 0; j < 4; ++j) {
                qp[i][j] = elu1f(qp[i][j]);
                zacc[i] += qp[i][j] * ks[f0 + tx * 4 + j];
            }
        #pragma unroll
        for (int i = 0; i < 4; ++i) {
            float4 v; v.x = qp[i][0]; v.y = qp[i][1]; v.z = qp[i][2]; v.w = qp[i][3];
            *(float4*)&QP[ty * 4 + i][tx * 4] = v;
        }
        __syncthreads();   // QP ready; Sb(proj) reads done

        #pragma unroll
        for (int l = 0; l < 4; ++l) {
            int f4 = tid + l * 256;
            int r = f4 >> 4, c4 = f4 & 15;
            *(float4*)&Sb[r][c4 * 4] =
                *(const float4*)&kv[((size_t)bh * 256 + f0 + r) * 64 + c4 * 4];
        }
        __syncthreads();

        #pragma unroll
        for (int ff0 = 0; ff0 < 64; ff0 += 4) {
            float a[4][4], bv[4][4];
            #pragma unroll
            for (int i = 0; i < 4; ++i)
                *(float4*)&a[i][0] = *(const float4*)&QP[ty * 4 + i][ff0];
            #pragma unroll
            for (int fx = 0; fx < 4; ++fx)
                *(float4*)&bv[fx][0] = *(const float4*)&Sb[ff0 + fx][tx * 4];
            #pragma unroll
            for (int i = 0; i < 4; ++i)
                #pragma unroll
                for (int fx = 0; fx < 4; ++fx) {
                    float av = a[i][fx];
                    #pragma unroll
                    for (int j = 0; j < 4; ++j) attnacc[i][j] += av * bv[fx][j];
                }
        }
    }

    // z reduce across tx (lane bits 0..3)
    #pragma unroll
    for (int i = 0; i < 4; ++i) {
        #pragma unroll
        for (int off = 8; off; off >>= 1)
            zacc[i] += __shfl_xor(zacc[i], off, 64);
    }
    #pragma unroll
    for (int i = 0; i < 4; ++i) {
        float z = 1.0f / (zacc[i] + 1e-8f);
        float4 v;
        v.x = attnacc[i][0] * z; v.y = attnacc[i][1] * z;
        v.z = attnacc[i][2] * z; v.w = attnacc[i][3] * z;
        *(float4*)&attn[((size_t)b * NTOK + n0 + ty * 4 + i) * DIM + h * 64 + tx * 4] = v;
    }
}

// ---------------------------------------------------------------------------
extern "C" void kernel_launch(void* const* d_in, const int* in_sizes, int n_in,
                              void* d_out, int out_size, void* d_ws, size_t ws_size,
                              hipStream_t stream)
{
    const float* x      = (const float*)d_in[0];
    const float* w_qkv  = (const float*)d_in[1];
    const float* proj   = (const float*)d_in[2];
    const float* w_out  = (const float*)d_in[3];
    const float* b_out  = (const float*)d_in[4];
    float* out = (float*)d_out;
    float* ws  = (float*)d_ws;

    if (ws_size < (size_t)WS_FLOATS * sizeof(float)) return;  // visible failure, not a fault

    float* kvbuf = ws + OFF_KVBUF;
    float* attn  = ws + OFF_ATTN;
    float* kv    = ws + OFF_KV;
    float* ksum  = ws + OFF_KSUM;

    zero_kernel<<<1024, 256, 0, stream>>>((float4*)kv, ZERO_F4);  // kv + ksum

    dim3 blk(256);
    for (int b = 0; b < NB; ++b) {
        // k,v for batch b: x_b(4096x1024) @ w_qkv[:,1024:3072] -> kvbuf(4096x2048)
        sgemm_kernel<<<dim3(2048 / 128, 4096 / 128), blk, 0, stream>>>(
            x + (size_t)b * NTOK * DIM, w_qkv + 1024, nullptr, kvbuf,
            4096, 2048, 1024, DIM, H3, 2048, 0);
        kv_kernel<<<dim3(8, 4, 16), blk, 0, stream>>>(kvbuf, proj, kv, ksum, b);
    }
    attn_kernel<<<dim3(64, 64), blk, 0, stream>>>(x, w_qkv, proj, kv, ksum, attn);
    sgemm_kernel<<<dim3(DIM / 128, ROWS / 128), blk, 0, stream>>>(
        attn, w_out, b_out, out, ROWS, DIM, DIM, DIM, DIM, DIM, 1);
}

// Round 3
// 1732.958 us; speedup vs baseline: 1.4703x; 1.4703x over previous
//
#include <hip/hip_runtime.h>

// LinearPerformerAttention on MI355X — round 3: split-bf16 MFMA for GEMM1/GEMM2.
// B=4, N=4096, DIM=1024, H=16, HD=64, FEAT=256.
// attn_kernel / kv_kernel / zero_kernel unchanged from the passing round-2 code.

#define NTOK 4096
#define NB 4
#define ROWS 16384
#define DIM 1024
#define H3 3072
#define FEAT 256

// workspace float offsets (total 117.5 MB — proven sufficient in round 2)
#define OFF_KVBUF 0u
#define OFF_ATTN  8388608u     // 4096*2048
#define OFF_KV    25165824u    // OFF_ATTN + 16384*1024
#define OFF_KSUM  29360128u    // OFF_KV + 64*256*64
#define WS_FLOATS 29376512u
#define ZERO_F4   1052672u     // (kv + ksum) / 4

typedef short short8 __attribute__((ext_vector_type(8)));
typedef float f32x4  __attribute__((ext_vector_type(4)));

__device__ __forceinline__ float elu1f(float v) {
    return v > 0.f ? v + 1.f : __expf(v);
}
__device__ __forceinline__ unsigned short f2bf(float f) {
    unsigned u = __float_as_uint(f);
    u += 0x7fffu + ((u >> 16) & 1u);
    return (unsigned short)(u >> 16);
}
__device__ __forceinline__ float bf2f(unsigned short s) {
    return __uint_as_float((unsigned)s << 16);
}

__global__ void zero_kernel(float4* p, unsigned n4) {
    for (unsigned i = blockIdx.x * blockDim.x + threadIdx.x; i < n4;
         i += gridDim.x * blockDim.x)
        p[i] = make_float4(0.f, 0.f, 0.f, 0.f);
}

// ---------------------------------------------------------------------------
// Pre-convert weight W (fp32, [K][N] slice at col_off, row stride ldw) into
// MFMA-tiled bf16 hi/lo planes. Tile = 32k x 128n. Per tile (8192 ushort):
// unit flat = hl*512 + kgrp*128 + col, each unit = 8 consecutive-k bf16.
// grid: K/32 * N/128 blocks (tt = kt*NT + nt), 256 threads.
// ---------------------------------------------------------------------------
__global__ __launch_bounds__(256) void preconv_kernel(
    const float* __restrict__ W, int ldw, int col_off, int NT,
    unsigned short* __restrict__ pre)
{
    __shared__ float T[32][136];   // padded: 136*4B row stride keeps f4 stores aligned
    const int tt = blockIdx.x;
    const int kt = tt / NT, nt = tt % NT;
    const int tid = threadIdx.x;

    #pragma unroll
    for (int i = 0; i < 4; ++i) {
        int f = tid + i * 256;
        int r = f >> 5, c4 = f & 31;
        float4 v = *(const float4*)&W[(size_t)(kt * 32 + r) * ldw + col_off + nt * 128 + c4 * 4];
        *(float4*)&T[r][c4 * 4] = v;
    }
    __syncthreads();

    #pragma unroll
    for (int half = 0; half < 2; ++half) {
        int u = tid + half * 256;          // 512 (kgrp,col) units
        int kg = u >> 7, col = u & 127;
        unsigned short hi[8], lo[8];
        #pragma unroll
        for (int j = 0; j < 8; ++j) {
            float f = T[kg * 8 + j][col];
            hi[j] = f2bf(f);
            lo[j] = f2bf(f - bf2f(hi[j]));
        }
        uint4 ph, pl;
        ph.x = (unsigned)hi[0] | ((unsigned)hi[1] << 16);
        ph.y = (unsigned)hi[2] | ((unsigned)hi[3] << 16);
        ph.z = (unsigned)hi[4] | ((unsigned)hi[5] << 16);
        ph.w = (unsigned)hi[6] | ((unsigned)hi[7] << 16);
        pl.x = (unsigned)lo[0] | ((unsigned)lo[1] << 16);
        pl.y = (unsigned)lo[2] | ((unsigned)lo[3] << 16);
        pl.z = (unsigned)lo[4] | ((unsigned)lo[5] << 16);
        pl.w = (unsigned)lo[6] | ((unsigned)lo[7] << 16);
        size_t base = (size_t)tt * 1024;
        *(uint4*)&pre[(base + 0   + kg * 128 + col) * 8] = ph;  // hi plane
        *(uint4*)&pre[(base + 512 + kg * 128 + col) * 8] = pl;  // lo plane
    }
}

// ---------------------------------------------------------------------------
// Split-bf16 MFMA GEMM: C = A(fp32 MxK, lda) @ Wpre [+bias].
// 128x128 tile, BK=32, 256 thr = 4 waves (2x2), wave tile 64x64 = 4x4 frags
// of 16x16. 3 MFMA per logical product (hi*hi + hi*lo + lo*hi).
// LDS 32KB: A_hi[4][128][16B] | A_lo | B_hi | B_lo. B staged via
// global_load_lds(16B) from pre-tiled weights; A converted in-kernel.
// ---------------------------------------------------------------------------
__global__ __launch_bounds__(256) void mfma_gemm(
    const float* __restrict__ A, const unsigned short* __restrict__ Bpre,
    const float* __restrict__ bias, float* __restrict__ C,
    int K, int lda, int ldc, int NT, int hasBias)
{
    __shared__ __align__(16) char smem[32768];
    const int tid = threadIdx.x;
    const int w = tid >> 6, l = tid & 63;
    const int wm = w >> 1, wn = w & 1;
    const int lg = l >> 4, li = l & 15;
    const int nt = blockIdx.x, mt = blockIdx.y;
    const int row0 = mt * 128, col0 = nt * 128;

    f32x4 acc[4][4] = {};

    const int nkt = K >> 5;
    for (int kt = 0; kt < nkt; ++kt) {
        // --- stage A (fp32 -> bf16 hi/lo), units kgrp-major so quarter-wave
        //     LDS writes are 256B-contiguous (conflict-free) ---
        #pragma unroll
        for (int half = 0; half < 2; ++half) {
            int u = tid + half * 256;
            int kg = u >> 7, row = u & 127;
            const float* ap = A + (size_t)(row0 + row) * lda + kt * 32 + kg * 8;
            float4 v0 = *(const float4*)ap;
            float4 v1 = *(const float4*)(ap + 4);
            float f[8] = {v0.x, v0.y, v0.z, v0.w, v1.x, v1.y, v1.z, v1.w};
            unsigned short hi[8], lo[8];
            #pragma unroll
            for (int j = 0; j < 8; ++j) {
                hi[j] = f2bf(f[j]);
                lo[j] = f2bf(f[j] - bf2f(hi[j]));
            }
            uint4 ph, pl;
            ph.x = (unsigned)hi[0] | ((unsigned)hi[1] << 16);
            ph.y = (unsigned)hi[2] | ((unsigned)hi[3] << 16);
            ph.z = (unsigned)hi[4] | ((unsigned)hi[5] << 16);
            ph.w = (unsigned)hi[6] | ((unsigned)hi[7] << 16);
            pl.x = (unsigned)lo[0] | ((unsigned)lo[1] << 16);
            pl.y = (unsigned)lo[2] | ((unsigned)lo[3] << 16);
            pl.z = (unsigned)lo[4] | ((unsigned)lo[5] << 16);
            pl.w = (unsigned)lo[6] | ((unsigned)lo[7] << 16);
            *(uint4*)(smem +        kg * 2048 + row * 16) = ph;
            *(uint4*)(smem + 8192 + kg * 2048 + row * 16) = pl;
        }
        // --- stage B: 16 chunks of 1KB, 4 per wave, direct global->LDS ---
        {
            const unsigned short* tsrc = Bpre + (size_t)(kt * NT + nt) * 8192;
            #pragma unroll
            for (int i = 0; i < 4; ++i) {
                int c = w * 4 + i;
                const unsigned short* s = tsrc + (size_t)c * 512 + (size_t)l * 8;
                char* d = smem + 16384 + c * 1024;
                __builtin_amdgcn_global_load_lds(
                    (const __attribute__((address_space(1))) unsigned int*)s,
                    (__attribute__((address_space(3))) unsigned int*)d, 16, 0, 0);
            }
        }
        __syncthreads();

        // --- fragments + MFMA ---
        short8 ah[4], al_[4], bh[4], bl_[4];
        #pragma unroll
        for (int fm = 0; fm < 4; ++fm) {
            int row = wm * 64 + fm * 16 + li;
            ah[fm]  = *(const short8*)(smem +        lg * 2048 + row * 16);
            al_[fm] = *(const short8*)(smem + 8192 + lg * 2048 + row * 16);
        }
        #pragma unroll
        for (int fn = 0; fn < 4; ++fn) {
            int col = wn * 64 + fn * 16 + li;
            bh[fn]  = *(const short8*)(smem + 16384 + lg * 2048 + col * 16);
            bl_[fn] = *(const short8*)(smem + 24576 + lg * 2048 + col * 16);
        }
        #pragma unroll
        for (int fm = 0; fm < 4; ++fm)
            #pragma unroll
            for (int fn = 0; fn < 4; ++fn) {
                acc[fm][fn] = __builtin_amdgcn_mfma_f32_16x16x32_bf16(ah[fm], bh[fn], acc[fm][fn], 0, 0, 0);
                acc[fm][fn] = __builtin_amdgcn_mfma_f32_16x16x32_bf16(ah[fm], bl_[fn], acc[fm][fn], 0, 0, 0);
                acc[fm][fn] = __builtin_amdgcn_mfma_f32_16x16x32_bf16(al_[fm], bh[fn], acc[fm][fn], 0, 0, 0);
            }
        __syncthreads();
    }

    // --- epilogue: D layout col=lane&15, row=(lane>>4)*4+reg (verified m89/m91) ---
    float bv[4];
    #pragma unroll
    for (int fn = 0; fn < 4; ++fn)
        bv[fn] = hasBias ? bias[col0 + wn * 64 + fn * 16 + li] : 0.f;
    #pragma unroll
    for (int fm = 0; fm < 4; ++fm) {
        #pragma unroll
        for (int fn = 0; fn < 4; ++fn) {
            int col = col0 + wn * 64 + fn * 16 + li;
            #pragma unroll
            for (int r = 0; r < 4; ++r) {
                int row = row0 + wm * 64 + fm * 16 + lg * 4 + r;
                C[(size_t)row * ldc + col] = acc[fm][fn][r] + bv[fn];
            }
        }
    }
}

// ---------------------------------------------------------------------------
// Kernel 2 (unchanged): fused proj/elu/kv-state per (n-split, f-chunk, h).
// ---------------------------------------------------------------------------
__global__ __launch_bounds__(256) void kv_kernel(
    const float* __restrict__ kvbuf, const float* __restrict__ proj,
    float* __restrict__ kv, float* __restrict__ ksum, int b)
{
    __shared__ float Kl[64][68];
    __shared__ float Vl[64][64];
    __shared__ float Pl[64][64];
    const int tid = threadIdx.x;
    const int tx = tid & 15, ty = tid >> 4;
    const int ns = blockIdx.x, fc = blockIdx.y, h = blockIdx.z;
    const int bh = b * 16 + h;
    const int f0 = fc * 64;

    #pragma unroll
    for (int l = 0; l < 4; ++l) {
        int f4 = tid + l * 256;
        int kk = f4 >> 4, c4 = f4 & 15;
        *(float4*)&Pl[kk][c4 * 4] =
            *(const float4*)&proj[(size_t)(h * 64 + kk) * 256 + f0 + c4 * 4];
    }
    const float* kbase = kvbuf + h * 64;
    const float* vbase = kvbuf + 1024 + h * 64;

    float kvacc[4][4] = {};
    float ksacc[4] = {};
    __syncthreads();

    for (int t = 0; t < 8; ++t) {
        const int n0 = ns * 512 + t * 64;
        #pragma unroll
        for (int l = 0; l < 4; ++l) {
            int f4 = tid + l * 256;
            int r = f4 >> 4, c4 = f4 & 15;
            *(float4*)&Kl[r][c4 * 4] = *(const float4*)&kbase[(size_t)(n0 + r) * 2048 + c4 * 4];
            *(float4*)&Vl[r][c4 * 4] = *(const float4*)&vbase[(size_t)(n0 + r) * 2048 + c4 * 4];
        }
        __syncthreads();

        float kp[4][4] = {};
        #pragma unroll
        for (int kk0 = 0; kk0 < 64; kk0 += 4) {
            float a[4][4], bb[4][4];
            #pragma unroll
            for (int i = 0; i < 4; ++i)
                *(float4*)&a[i][0] = *(const float4*)&Kl[ty * 4 + i][kk0];
            #pragma unroll
            for (int kx = 0; kx < 4; ++kx)
                *(float4*)&bb[kx][0] = *(const float4*)&Pl[kk0 + kx][tx * 4];
            #pragma unroll
            for (int i = 0; i < 4; ++i)
                #pragma unroll
                for (int kx = 0; kx < 4; ++kx) {
                    float av = a[i][kx];
                    #pragma unroll
                    for (int j = 0; j < 4; ++j) kp[i][j] += av * bb[kx][j];
                }
        }
        #pragma unroll
        for (int i = 0; i < 4; ++i)
            #pragma unroll
            for (int j = 0; j < 4; ++j) kp[i][j] = elu1f(kp[i][j]);

        __syncthreads();
        #pragma unroll
        for (int i = 0; i < 4; ++i) {
            float4 v; v.x = kp[i][0]; v.y = kp[i][1]; v.z = kp[i][2]; v.w = kp[i][3];
            *(float4*)&Kl[ty * 4 + i][tx * 4] = v;
        }
        __syncthreads();

        #pragma unroll
        for (int nn = 0; nn < 64; ++nn) {
            float a[4], bv[4];
            *(float4*)&a[0]  = *(const float4*)&Kl[nn][ty * 4];
            *(float4*)&bv[0] = *(const float4*)&Vl[nn][tx * 4];
            #pragma unroll
            for (int i = 0; i < 4; ++i) ksacc[i] += a[i];
            #pragma unroll
            for (int i = 0; i < 4; ++i)
                #pragma unroll
                for (int j = 0; j < 4; ++j) kvacc[i][j] += a[i] * bv[j];
        }
        __syncthreads();
    }

    float* kvdst = kv + ((size_t)bh * 256 + f0) * 64;
    #pragma unroll
    for (int i = 0; i < 4; ++i)
        #pragma unroll
        for (int j = 0; j < 4; ++j)
            atomicAdd(&kvdst[(size_t)(ty * 4 + i) * 64 + tx * 4 + j], kvacc[i][j]);
    if (tx == 0) {
        #pragma unroll
        for (int i = 0; i < 4; ++i)
            atomicAdd(&ksum[(size_t)bh * 256 + f0 + ty * 4 + i], ksacc[i]);
    }
}

// ---------------------------------------------------------------------------
// Kernel 3 (unchanged): fused q-gemm/proj/elu/attn/z, head-interleaved output.
// ---------------------------------------------------------------------------
__global__ __launch_bounds__(256) void attn_kernel(
    const float* __restrict__ x, const float* __restrict__ w_qkv,
    const float* __restrict__ proj, const float* __restrict__ kv,
    const float* __restrict__ ksum, float* __restrict__ attn)
{
    __shared__ float Ql[64][68];
    __shared__ float Sb[64][64];
    __shared__ float QP[64][68];
    __shared__ float ks[256];
    const int tid = threadIdx.x;
    const int tx = tid & 15, ty = tid >> 4;
    const int nt = blockIdx.x, bh = blockIdx.y;
    const int b = bh >> 4, h = bh & 15;
    const int n0 = nt * 64;

    ks[tid] = ksum[(size_t)bh * 256 + tid];

    float qacc[4][4] = {};
    for (int kk0 = 0; kk0 < 1024; kk0 += 64) {
        __syncthreads();
        #pragma unroll
        for (int l = 0; l < 4; ++l) {
            int f4 = tid + l * 256;
            int r = f4 >> 4, c4 = f4 & 15;
            *(float4*)&Sb[r][c4 * 4] =
                *(const float4*)&x[(size_t)(b * NTOK + n0 + r) * DIM + kk0 + c4 * 4];
            *(float4*)&QP[r][c4 * 4] =
                *(const float4*)&w_qkv[(size_t)(kk0 + r) * H3 + h * 64 + c4 * 4];
        }
        __syncthreads();
        #pragma unroll
        for (int kx0 = 0; kx0 < 64; kx0 += 4) {
            float a[4][4], bb[4][4];
            #pragma unroll
            for (int i = 0; i < 4; ++i)
                *(float4*)&a[i][0] = *(const float4*)&Sb[ty * 4 + i][kx0];
            #pragma unroll
            for (int kx = 0; kx < 4; ++kx)
                *(float4*)&bb[kx][0] = *(const float4*)&QP[kx0 + kx][tx * 4];
            #pragma unroll
            for (int i = 0; i < 4; ++i)
                #pragma unroll
                for (int kx = 0; kx < 4; ++kx) {
                    float av = a[i][kx];
                    #pragma unroll
                    for (int j = 0; j < 4; ++j) qacc[i][j] += av * bb[kx][j];
                }
        }
    }
    __syncthreads();
    #pragma unroll
    for (int i = 0; i < 4; ++i) {
        float4 v; v.x = qacc[i][0]; v.y = qacc[i][1]; v.z = qacc[i][2]; v.w = qacc[i][3];
        *(float4*)&Ql[ty * 4 + i][tx * 4] = v;
    }

    float attnacc[4][4] = {};
    float zacc[4] = {};

    for (int fc = 0; fc < 4; ++fc) {
        const int f0 = fc * 64;
        __syncthreads();
        #pragma unroll
        for (int l = 0; l < 4; ++l) {
            int f4 = tid + l * 256;
            int kk = f4 >> 4, c4 = f4 & 15;
            *(float4*)&Sb[kk][c4 * 4] =
                *(const float4*)&proj[(size_t)(h * 64 + kk) * 256 + f0 + c4 * 4];
        }
        __syncthreads();

        float qp[4][4] = {};
        #pragma unroll
        for (int kk0 = 0; kk0 < 64; kk0 += 4) {
            float a[4][4], bb[4][4];
            #pragma unroll
            for (int i = 0; i < 4; ++i)
                *(float4*)&a[i][0] = *(const float4*)&Ql[ty * 4 + i][kk0];
            #pragma unroll
            for (int kx = 0; kx < 4; ++kx)
                *(float4*)&bb[kx][0] = *(const float4*)&Sb[kk0 + kx][tx * 4];
            #pragma unroll
            for (int i = 0; i < 4; ++i)
                #pragma unroll
                for (int kx = 0; kx < 4; ++kx) {
                    float av = a[i][kx];
                    #pragma unroll
                    for (int j = 0; j < 4; ++j) qp[i][j] += av * bb[kx][j];
                }
        }
        #pragma unroll
        for (int i = 0; i < 4; ++i)
            #pragma unroll
            for (int j = 0; j < 4; ++j) {
                qp[i][j] = elu1f(qp[i][j]);
                zacc[i] += qp[i][j] * ks[f0 + tx * 4 + j];
            }
        #pragma unroll
        for (int i = 0; i < 4; ++i) {
            float4 v; v.x = qp[i][0]; v.y = qp[i][1]; v.z = qp[i][2]; v.w = qp[i][3];
            *(float4*)&QP[ty * 4 + i][tx * 4] = v;
        }
        __syncthreads();

        #pragma unroll
        for (int l = 0; l < 4; ++l) {
            int f4 = tid + l * 256;
            int r = f4 >> 4, c4 = f4 & 15;
            *(float4*)&Sb[r][c4 * 4] =
                *(const float4*)&kv[((size_t)bh * 256 + f0 + r) * 64 + c4 * 4];
        }
        __syncthreads();

        #pragma unroll
        for (int ff0 = 0; ff0 < 64; ff0 += 4) {
            float a[4][4], bv[4][4];
            #pragma unroll
            for (int i = 0; i < 4; ++i)
                *(float4*)&a[i][0] = *(const float4*)&QP[ty * 4 + i][ff0];
            #pragma unroll
            for (int fx = 0; fx < 4; ++fx)
                *(float4*)&bv[fx][0] = *(const float4*)&Sb[ff0 + fx][tx * 4];
            #pragma unroll
            for (int i = 0; i < 4; ++i)
                #pragma unroll
                for (int fx = 0; fx < 4; ++fx) {
                    float av = a[i][fx];
                    #pragma unroll
                    for (int j = 0; j < 4; ++j) attnacc[i][j] += av * bv[fx][j];
                }
        }
    }

    #pragma unroll
    for (int i = 0; i < 4; ++i) {
        #pragma unroll
        for (int off = 8; off; off >>= 1)
            zacc[i] += __shfl_xor(zacc[i], off, 64);
    }
    #pragma unroll
    for (int i = 0; i < 4; ++i) {
        float z = 1.0f / (zacc[i] + 1e-8f);
        float4 v;
        v.x = attnacc[i][0] * z; v.y = attnacc[i][1] * z;
        v.z = attnacc[i][2] * z; v.w = attnacc[i][3] * z;
        *(float4*)&attn[((size_t)b * NTOK + n0 + ty * 4 + i) * DIM + h * 64 + tx * 4] = v;
    }
}

// ---------------------------------------------------------------------------
extern "C" void kernel_launch(void* const* d_in, const int* in_sizes, int n_in,
                              void* d_out, int out_size, void* d_ws, size_t ws_size,
                              hipStream_t stream)
{
    const float* x      = (const float*)d_in[0];
    const float* w_qkv  = (const float*)d_in[1];
    const float* proj   = (const float*)d_in[2];
    const float* w_out  = (const float*)d_in[3];
    const float* b_out  = (const float*)d_in[4];
    float* out = (float*)d_out;
    float* ws  = (float*)d_ws;

    if (ws_size < (size_t)WS_FLOATS * sizeof(float)) return;

    float* kvbuf = ws + OFF_KVBUF;
    float* attn  = ws + OFF_ATTN;
    float* kv    = ws + OFF_KV;
    float* ksum  = ws + OFF_KSUM;
    // pre-converted weights live in regions that are dead at their use time:
    unsigned short* wkv_pre  = (unsigned short*)(ws + OFF_ATTN);   // dead once attn_kernel writes
    unsigned short* wout_pre = (unsigned short*)(ws + OFF_KVBUF);  // kvbuf dead after kv phase

    zero_kernel<<<1024, 256, 0, stream>>>((float4*)kv, ZERO_F4);

    dim3 blk(256);
    // pre-convert w_qkv[:,1024:3072] -> tiled bf16 hi/lo (512 tiles)
    preconv_kernel<<<512, blk, 0, stream>>>(w_qkv, H3, 1024, 16, wkv_pre);

    for (int b = 0; b < NB; ++b) {
        // k,v for batch b: x_b(4096x1024) @ Wkv -> kvbuf(4096x2048)
        mfma_gemm<<<dim3(16, 32), blk, 0, stream>>>(
            x + (size_t)b * NTOK * DIM, wkv_pre, nullptr, kvbuf,
            1024, DIM, 2048, 16, 0);
        kv_kernel<<<dim3(8, 4, 16), blk, 0, stream>>>(kvbuf, proj, kv, ksum, b);
    }
    attn_kernel<<<dim3(64, 64), blk, 0, stream>>>(x, w_qkv, proj, kv, ksum, attn);

    // pre-convert w_out (256 tiles) into kvbuf region, then out GEMM + bias
    preconv_kernel<<<256, blk, 0, stream>>>(w_out, DIM, 0, 8, wout_pre);
    mfma_gemm<<<dim3(8, 128), blk, 0, stream>>>(
        attn, wout_pre, b_out, out, 1024, DIM, DIM, 8, 1);
}

// Round 4
// 1208.870 us; speedup vs baseline: 2.1078x; 1.4335x over previous
//
#include <hip/hip_runtime.h>

// LinearPerformerAttention on MI355X — round 4: MFMA everywhere except kv_kernel.
// B=4, N=4096, DIM=1024, H=16, HD=64, FEAT=256.
// Phases: [per-b kv-GEMM + kv_kernel] -> kvconv -> [per-b q-GEMM + attn_mfma] -> out-GEMM.

#define NTOK 4096
#define NB 4
#define ROWS 16384
#define DIM 1024
#define H3 3072
#define FEAT 256

// workspace float offsets (97.6 MB total; 117.5 MB proven available)
#define OFF_KV      0u
#define OFF_KSUM    1048576u
#define OFF_PROJPRE 1064960u
#define OFF_KVPRE   1327104u
#define OFF_ATTN    2375680u                 // 16,777,216 fl
#define OFF_KVBUF   OFF_ATTN                 // overlay, phase-1 only
#define OFF_WKVPRE  10764288u                // overlay, phase-1 only
#define OFF_QBUF    19152896u                // 4,194,304 fl
#define OFF_WOUTPRE OFF_QBUF                 // overlay, phase-3 only
#define OFF_WQPRE   23347200u
#define WS_FLOATS   24395776u
#define ZERO_F4     266240u                  // (kv + ksum)/4

typedef short short8 __attribute__((ext_vector_type(8)));
typedef float f32x4  __attribute__((ext_vector_type(4)));
typedef unsigned short us4 __attribute__((ext_vector_type(4)));

__device__ __forceinline__ float elu1f(float v) {
    return v > 0.f ? v + 1.f : __expf(v);
}
__device__ __forceinline__ unsigned short f2bf(float f) {
    unsigned u = __float_as_uint(f);
    u += 0x7fffu + ((u >> 16) & 1u);
    return (unsigned short)(u >> 16);
}
__device__ __forceinline__ float bf2f(unsigned short s) {
    return __uint_as_float((unsigned)s << 16);
}

__global__ void zero_kernel(float4* p, unsigned n4) {
    for (unsigned i = blockIdx.x * blockDim.x + threadIdx.x; i < n4;
         i += gridDim.x * blockDim.x)
        p[i] = make_float4(0.f, 0.f, 0.f, 0.f);
}

// ---------------------------------------------------------------------------
// Weight pre-convert (unchanged, round-3 verified): fp32 [K][N] slice ->
// MFMA-tiled bf16 hi/lo. Tile 32k x 128n; unit = 8 consecutive-k bf16.
// ---------------------------------------------------------------------------
__global__ __launch_bounds__(256) void preconv_kernel(
    const float* __restrict__ W, int ldw, int col_off, int NT,
    unsigned short* __restrict__ pre)
{
    __shared__ float T[32][136];
    const int tt = blockIdx.x;
    const int kt = tt / NT, nt = tt % NT;
    const int tid = threadIdx.x;

    #pragma unroll
    for (int i = 0; i < 4; ++i) {
        int f = tid + i * 256;
        int r = f >> 5, c4 = f & 31;
        float4 v = *(const float4*)&W[(size_t)(kt * 32 + r) * ldw + col_off + nt * 128 + c4 * 4];
        *(float4*)&T[r][c4 * 4] = v;
    }
    __syncthreads();

    #pragma unroll
    for (int half = 0; half < 2; ++half) {
        int u = tid + half * 256;
        int kg = u >> 7, col = u & 127;
        unsigned short hi[8], lo[8];
        #pragma unroll
        for (int j = 0; j < 8; ++j) {
            float f = T[kg * 8 + j][col];
            hi[j] = f2bf(f);
            lo[j] = f2bf(f - bf2f(hi[j]));
        }
        uint4 ph, pl;
        ph.x = (unsigned)hi[0] | ((unsigned)hi[1] << 16);
        ph.y = (unsigned)hi[2] | ((unsigned)hi[3] << 16);
        ph.z = (unsigned)hi[4] | ((unsigned)hi[5] << 16);
        ph.w = (unsigned)hi[6] | ((unsigned)hi[7] << 16);
        pl.x = (unsigned)lo[0] | ((unsigned)lo[1] << 16);
        pl.y = (unsigned)lo[2] | ((unsigned)lo[3] << 16);
        pl.z = (unsigned)lo[4] | ((unsigned)lo[5] << 16);
        pl.w = (unsigned)lo[6] | ((unsigned)lo[7] << 16);
        size_t base = (size_t)tt * 1024;
        *(uint4*)&pre[(base + 0   + kg * 128 + col) * 8] = ph;
        *(uint4*)&pre[(base + 512 + kg * 128 + col) * 8] = pl;
    }
}

// ---------------------------------------------------------------------------
// proj -> A-frag layout (P^T): per (h,fc): 8192 shorts = hi[512 units]+lo[512],
// unit (kgHD 0..7, f 0..63) = 8 hd-consecutive bf16 of proj[hd][fc*64+f].
// grid 64 = h*4+fc.
// ---------------------------------------------------------------------------
__global__ __launch_bounds__(256) void projconv_kernel(
    const float* __restrict__ proj, unsigned short* __restrict__ pre)
{
    const int blk = blockIdx.x;
    const int h = blk >> 2, fc = blk & 3;
    const int tid = threadIdx.x;
    #pragma unroll
    for (int u0 = 0; u0 < 2; ++u0) {
        int u = tid * 2 + u0;
        int kg = u >> 6, f = u & 63;
        unsigned short hi[8], lo[8];
        #pragma unroll
        for (int j = 0; j < 8; ++j) {
            float v = proj[(size_t)(h * 64 + kg * 8 + j) * 256 + fc * 64 + f];
            hi[j] = f2bf(v);
            lo[j] = f2bf(v - bf2f(hi[j]));
        }
        uint4 ph, pl;
        ph.x = (unsigned)hi[0] | ((unsigned)hi[1] << 16);
        ph.y = (unsigned)hi[2] | ((unsigned)hi[3] << 16);
        ph.z = (unsigned)hi[4] | ((unsigned)hi[5] << 16);
        ph.w = (unsigned)hi[6] | ((unsigned)hi[7] << 16);
        pl.x = (unsigned)lo[0] | ((unsigned)lo[1] << 16);
        pl.y = (unsigned)lo[2] | ((unsigned)lo[3] << 16);
        pl.z = (unsigned)lo[4] | ((unsigned)lo[5] << 16);
        pl.w = (unsigned)lo[6] | ((unsigned)lo[7] << 16);
        size_t base = (size_t)blk * 8192;
        *(uint4*)&pre[base + (size_t)(kg * 64 + f) * 8] = ph;
        *(uint4*)&pre[base + 4096 + (size_t)(kg * 64 + f) * 8] = pl;
    }
}

// ---------------------------------------------------------------------------
// kv state -> B-frag layout: per (bh,fc): 8192 shorts hi+lo,
// unit (kgF 0..7, d 0..63) = 8 f-consecutive bf16 of kv[fc*64+f][d].
// grid 256 = bh*4+fc.
// ---------------------------------------------------------------------------
__global__ __launch_bounds__(256) void kvconv_kernel(
    const float* __restrict__ kvst, unsigned short* __restrict__ pre)
{
    const int blk = blockIdx.x;
    const int bh = blk >> 2, fc = blk & 3;
    const int tid = threadIdx.x;
    #pragma unroll
    for (int u0 = 0; u0 < 2; ++u0) {
        int u = tid * 2 + u0;
        int kg = u >> 6, d = u & 63;
        unsigned short hi[8], lo[8];
        #pragma unroll
        for (int j = 0; j < 8; ++j) {
            float v = kvst[((size_t)bh * 256 + fc * 64 + kg * 8 + j) * 64 + d];
            hi[j] = f2bf(v);
            lo[j] = f2bf(v - bf2f(hi[j]));
        }
        uint4 ph, pl;
        ph.x = (unsigned)hi[0] | ((unsigned)hi[1] << 16);
        ph.y = (unsigned)hi[2] | ((unsigned)hi[3] << 16);
        ph.z = (unsigned)hi[4] | ((unsigned)hi[5] << 16);
        ph.w = (unsigned)hi[6] | ((unsigned)hi[7] << 16);
        pl.x = (unsigned)lo[0] | ((unsigned)lo[1] << 16);
        pl.y = (unsigned)lo[2] | ((unsigned)lo[3] << 16);
        pl.z = (unsigned)lo[4] | ((unsigned)lo[5] << 16);
        pl.w = (unsigned)lo[6] | ((unsigned)lo[7] << 16);
        size_t base = (size_t)blk * 8192;
        *(uint4*)&pre[base + (size_t)(kg * 64 + d) * 8] = ph;
        *(uint4*)&pre[base + 4096 + (size_t)(kg * 64 + d) * 8] = pl;
    }
}

// ---------------------------------------------------------------------------
// Split-bf16 MFMA GEMM (unchanged, round-3 verified).
// ---------------------------------------------------------------------------
__global__ __launch_bounds__(256) void mfma_gemm(
    const float* __restrict__ A, const unsigned short* __restrict__ Bpre,
    const float* __restrict__ bias, float* __restrict__ C,
    int K, int lda, int ldc, int NT, int hasBias)
{
    __shared__ __align__(16) char smem[32768];
    const int tid = threadIdx.x;
    const int w = tid >> 6, l = tid & 63;
    const int wm = w >> 1, wn = w & 1;
    const int lg = l >> 4, li = l & 15;
    const int nt = blockIdx.x, mt = blockIdx.y;
    const int row0 = mt * 128, col0 = nt * 128;

    f32x4 acc[4][4] = {};

    const int nkt = K >> 5;
    for (int kt = 0; kt < nkt; ++kt) {
        #pragma unroll
        for (int half = 0; half < 2; ++half) {
            int u = tid + half * 256;
            int kg = u >> 7, row = u & 127;
            const float* ap = A + (size_t)(row0 + row) * lda + kt * 32 + kg * 8;
            float4 v0 = *(const float4*)ap;
            float4 v1 = *(const float4*)(ap + 4);
            float f[8] = {v0.x, v0.y, v0.z, v0.w, v1.x, v1.y, v1.z, v1.w};
            unsigned short hi[8], lo[8];
            #pragma unroll
            for (int j = 0; j < 8; ++j) {
                hi[j] = f2bf(f[j]);
                lo[j] = f2bf(f[j] - bf2f(hi[j]));
            }
            uint4 ph, pl;
            ph.x = (unsigned)hi[0] | ((unsigned)hi[1] << 16);
            ph.y = (unsigned)hi[2] | ((unsigned)hi[3] << 16);
            ph.z = (unsigned)hi[4] | ((unsigned)hi[5] << 16);
            ph.w = (unsigned)hi[6] | ((unsigned)hi[7] << 16);
            pl.x = (unsigned)lo[0] | ((unsigned)lo[1] << 16);
            pl.y = (unsigned)lo[2] | ((unsigned)lo[3] << 16);
            pl.z = (unsigned)lo[4] | ((unsigned)lo[5] << 16);
            pl.w = (unsigned)lo[6] | ((unsigned)lo[7] << 16);
            *(uint4*)(smem +        kg * 2048 + row * 16) = ph;
            *(uint4*)(smem + 8192 + kg * 2048 + row * 16) = pl;
        }
        {
            const unsigned short* tsrc = Bpre + (size_t)(kt * NT + nt) * 8192;
            #pragma unroll
            for (int i = 0; i < 4; ++i) {
                int c = w * 4 + i;
                const unsigned short* s = tsrc + (size_t)c * 512 + (size_t)l * 8;
                char* d = smem + 16384 + c * 1024;
                __builtin_amdgcn_global_load_lds(
                    (const __attribute__((address_space(1))) unsigned int*)s,
                    (__attribute__((address_space(3))) unsigned int*)d, 16, 0, 0);
            }
        }
        __syncthreads();

        short8 ah[4], al_[4], bh[4], bl_[4];
        #pragma unroll
        for (int fm = 0; fm < 4; ++fm) {
            int row = wm * 64 + fm * 16 + li;
            ah[fm]  = *(const short8*)(smem +        lg * 2048 + row * 16);
            al_[fm] = *(const short8*)(smem + 8192 + lg * 2048 + row * 16);
        }
        #pragma unroll
        for (int fn = 0; fn < 4; ++fn) {
            int col = wn * 64 + fn * 16 + li;
            bh[fn]  = *(const short8*)(smem + 16384 + lg * 2048 + col * 16);
            bl_[fn] = *(const short8*)(smem + 24576 + lg * 2048 + col * 16);
        }
        #pragma unroll
        for (int fm = 0; fm < 4; ++fm)
            #pragma unroll
            for (int fn = 0; fn < 4; ++fn) {
                acc[fm][fn] = __builtin_amdgcn_mfma_f32_16x16x32_bf16(ah[fm], bh[fn], acc[fm][fn], 0, 0, 0);
                acc[fm][fn] = __builtin_amdgcn_mfma_f32_16x16x32_bf16(ah[fm], bl_[fn], acc[fm][fn], 0, 0, 0);
                acc[fm][fn] = __builtin_amdgcn_mfma_f32_16x16x32_bf16(al_[fm], bh[fn], acc[fm][fn], 0, 0, 0);
            }
        __syncthreads();
    }

    float bv[4];
    #pragma unroll
    for (int fn = 0; fn < 4; ++fn)
        bv[fn] = hasBias ? bias[col0 + wn * 64 + fn * 16 + li] : 0.f;
    #pragma unroll
    for (int fm = 0; fm < 4; ++fm) {
        #pragma unroll
        for (int fn = 0; fn < 4; ++fn) {
            int col = col0 + wn * 64 + fn * 16 + li;
            #pragma unroll
            for (int r = 0; r < 4; ++r) {
                int row = row0 + wm * 64 + fm * 16 + lg * 4 + r;
                C[(size_t)row * ldc + col] = acc[fm][fn][r] + bv[fn];
            }
        }
    }
}

// ---------------------------------------------------------------------------
// kv_kernel (unchanged, fp32; next-round MFMA target).
// ---------------------------------------------------------------------------
__global__ __launch_bounds__(256) void kv_kernel(
    const float* __restrict__ kvbuf, const float* __restrict__ proj,
    float* __restrict__ kv, float* __restrict__ ksum, int b)
{
    __shared__ float Kl[64][68];
    __shared__ float Vl[64][64];
    __shared__ float Pl[64][64];
    const int tid = threadIdx.x;
    const int tx = tid & 15, ty = tid >> 4;
    const int ns = blockIdx.x, fc = blockIdx.y, h = blockIdx.z;
    const int bh = b * 16 + h;
    const int f0 = fc * 64;

    #pragma unroll
    for (int l = 0; l < 4; ++l) {
        int f4 = tid + l * 256;
        int kk = f4 >> 4, c4 = f4 & 15;
        *(float4*)&Pl[kk][c4 * 4] =
            *(const float4*)&proj[(size_t)(h * 64 + kk) * 256 + f0 + c4 * 4];
    }
    const float* kbase = kvbuf + h * 64;
    const float* vbase = kvbuf + 1024 + h * 64;

    float kvacc[4][4] = {};
    float ksacc[4] = {};
    __syncthreads();

    for (int t = 0; t < 8; ++t) {
        const int n0 = ns * 512 + t * 64;
        #pragma unroll
        for (int l = 0; l < 4; ++l) {
            int f4 = tid + l * 256;
            int r = f4 >> 4, c4 = f4 & 15;
            *(float4*)&Kl[r][c4 * 4] = *(const float4*)&kbase[(size_t)(n0 + r) * 2048 + c4 * 4];
            *(float4*)&Vl[r][c4 * 4] = *(const float4*)&vbase[(size_t)(n0 + r) * 2048 + c4 * 4];
        }
        __syncthreads();

        float kp[4][4] = {};
        #pragma unroll
        for (int kk0 = 0; kk0 < 64; kk0 += 4) {
            float a[4][4], bb[4][4];
            #pragma unroll
            for (int i = 0; i < 4; ++i)
                *(float4*)&a[i][0] = *(const float4*)&Kl[ty * 4 + i][kk0];
            #pragma unroll
            for (int kx = 0; kx < 4; ++kx)
                *(float4*)&bb[kx][0] = *(const float4*)&Pl[kk0 + kx][tx * 4];
            #pragma unroll
            for (int i = 0; i < 4; ++i)
                #pragma unroll
                for (int kx = 0; kx < 4; ++kx) {
                    float av = a[i][kx];
                    #pragma unroll
                    for (int j = 0; j < 4; ++j) kp[i][j] += av * bb[kx][j];
                }
        }
        #pragma unroll
        for (int i = 0; i < 4; ++i)
            #pragma unroll
            for (int j = 0; j < 4; ++j) kp[i][j] = elu1f(kp[i][j]);

        __syncthreads();
        #pragma unroll
        for (int i = 0; i < 4; ++i) {
            float4 v; v.x = kp[i][0]; v.y = kp[i][1]; v.z = kp[i][2]; v.w = kp[i][3];
            *(float4*)&Kl[ty * 4 + i][tx * 4] = v;
        }
        __syncthreads();

        #pragma unroll
        for (int nn = 0; nn < 64; ++nn) {
            float a[4], bv[4];
            *(float4*)&a[0]  = *(const float4*)&Kl[nn][ty * 4];
            *(float4*)&bv[0] = *(const float4*)&Vl[nn][tx * 4];
            #pragma unroll
            for (int i = 0; i < 4; ++i) ksacc[i] += a[i];
            #pragma unroll
            for (int i = 0; i < 4; ++i)
                #pragma unroll
                for (int j = 0; j < 4; ++j) kvacc[i][j] += a[i] * bv[j];
        }
        __syncthreads();
    }

    float* kvdst = kv + ((size_t)bh * 256 + f0) * 64;
    #pragma unroll
    for (int i = 0; i < 4; ++i)
        #pragma unroll
        for (int j = 0; j < 4; ++j)
            atomicAdd(&kvdst[(size_t)(ty * 4 + i) * 64 + tx * 4 + j], kvacc[i][j]);
    if (tx == 0) {
        #pragma unroll
        for (int i = 0; i < 4; ++i)
            atomicAdd(&ksum[(size_t)bh * 256 + f0 + ty * 4 + i], ksacc[i]);
    }
}

// ---------------------------------------------------------------------------
// attn_mfma: per (64-token tile, head) of batch b.
// qp-MFMA swapped (D'[f][n] = P^T q^T): A = projpre frags, B = q in regs.
// elu + z from exact acc; qp -> bf16 hi/lo packed ds_write_b64 into A-layout
// LDS; attn-MFMA: D2[n][d] += qp * kvpre. grid (64, 16); 256 thr = 4 waves.
// ---------------------------------------------------------------------------
__global__ __launch_bounds__(256) void attn_mfma(
    const float* __restrict__ qbuf, const unsigned short* __restrict__ projpre,
    const unsigned short* __restrict__ kvpre, const float* __restrict__ ksum,
    float* __restrict__ attn, int b)
{
    __shared__ __align__(16) char smem[49152];   // QP 16K | BP 16K | BKV 16K
    char* QP  = smem;
    char* BP  = smem + 16384;
    char* BKV = smem + 32768;
    const int tid = threadIdx.x;
    const int w = tid >> 6, l = tid & 63;
    const int lg = l >> 4, li = l & 15;
    const int nt = blockIdx.x, h = blockIdx.y;
    const int bh = b * 16 + h;
    const int n0 = nt * 64;

    // q B-frags -> registers (lane: col n = w*16+li, k = (ks*4+lg)*8 .. +8)
    short8 qh[2], ql[2];
    {
        const float* qrow = qbuf + (size_t)(n0 + w * 16 + li) * 1024 + h * 64;
        #pragma unroll
        for (int ks = 0; ks < 2; ++ks) {
            int kc = (ks * 4 + lg) * 8;
            float4 v0 = *(const float4*)&qrow[kc];
            float4 v1 = *(const float4*)&qrow[kc + 4];
            float f[8] = {v0.x, v0.y, v0.z, v0.w, v1.x, v1.y, v1.z, v1.w};
            unsigned short hi[8], lo[8];
            #pragma unroll
            for (int j = 0; j < 8; ++j) {
                hi[j] = f2bf(f[j]);
                lo[j] = f2bf(f[j] - bf2f(hi[j]));
            }
            short8 qhv, qlv;
            #pragma unroll
            for (int j = 0; j < 8; ++j) { qhv[j] = (short)hi[j]; qlv[j] = (short)lo[j]; }
            qh[ks] = qhv; ql[ks] = qlv;
        }
    }

    f32x4 attnacc[4] = {};
    float zacc = 0.f;

    for (int fc = 0; fc < 4; ++fc) {
        // stage proj chunk + kv chunk (16 KB each, linear unit order)
        const unsigned short* psrc = projpre + (size_t)(h * 4 + fc) * 8192;
        const unsigned short* csrc = kvpre + (size_t)(bh * 4 + fc) * 8192;
        #pragma unroll
        for (int i = 0; i < 4; ++i) {
            int u = tid + i * 256;
            __builtin_amdgcn_global_load_lds(
                (const __attribute__((address_space(1))) unsigned int*)(psrc + (size_t)u * 8),
                (__attribute__((address_space(3))) unsigned int*)(BP + u * 16), 16, 0, 0);
            __builtin_amdgcn_global_load_lds(
                (const __attribute__((address_space(1))) unsigned int*)(csrc + (size_t)u * 8),
                (__attribute__((address_space(3))) unsigned int*)(BKV + u * 16), 16, 0, 0);
        }
        __syncthreads();

        // qp-MFMA: D'[f][n], 4 f-frags
        f32x4 accp[4] = {};
        #pragma unroll
        for (int ks = 0; ks < 2; ++ks) {
            #pragma unroll
            for (int ff = 0; ff < 4; ++ff) {
                int f = ff * 16 + li;
                short8 ah = *(const short8*)(BP +        (ks * 4 + lg) * 1024 + f * 16);
                short8 al = *(const short8*)(BP + 8192 + (ks * 4 + lg) * 1024 + f * 16);
                accp[ff] = __builtin_amdgcn_mfma_f32_16x16x32_bf16(ah, qh[ks], accp[ff], 0, 0, 0);
                accp[ff] = __builtin_amdgcn_mfma_f32_16x16x32_bf16(ah, ql[ks], accp[ff], 0, 0, 0);
                accp[ff] = __builtin_amdgcn_mfma_f32_16x16x32_bf16(al, qh[ks], accp[ff], 0, 0, 0);
            }
        }

        // elu + z (exact) + bf16 hi/lo pack -> QP (A-layout, b64 writes)
        #pragma unroll
        for (int ff = 0; ff < 4; ++ff) {
            float4 ks4 = *(const float4*)&ksum[(size_t)bh * 256 + fc * 64 + ff * 16 + lg * 4];
            float kse[4] = {ks4.x, ks4.y, ks4.z, ks4.w};
            us4 h4, l4;
            #pragma unroll
            for (int r = 0; r < 4; ++r) {
                float v = elu1f(accp[ff][r]);
                zacc += v * kse[r];
                unsigned short hv = f2bf(v);
                h4[r] = hv;
                l4[r] = f2bf(v - bf2f(hv));
            }
            int boff = (ff * 2 + (lg >> 1)) * 1024 + (w * 16 + li) * 16 + (lg & 1) * 8;
            *(us4*)(QP + boff) = h4;
            *(us4*)(QP + 8192 + boff) = l4;
        }
        __syncthreads();

        // attn-MFMA: D2[n][d] += qp @ kv_chunk
        #pragma unroll
        for (int ks = 0; ks < 2; ++ks) {
            short8 a2h = *(const short8*)(QP +        (ks * 4 + lg) * 1024 + (w * 16 + li) * 16);
            short8 a2l = *(const short8*)(QP + 8192 + (ks * 4 + lg) * 1024 + (w * 16 + li) * 16);
            #pragma unroll
            for (int fd = 0; fd < 4; ++fd) {
                int d = fd * 16 + li;
                short8 b2h = *(const short8*)(BKV +        (ks * 4 + lg) * 1024 + d * 16);
                short8 b2l = *(const short8*)(BKV + 8192 + (ks * 4 + lg) * 1024 + d * 16);
                attnacc[fd] = __builtin_amdgcn_mfma_f32_16x16x32_bf16(a2h, b2h, attnacc[fd], 0, 0, 0);
                attnacc[fd] = __builtin_amdgcn_mfma_f32_16x16x32_bf16(a2h, b2l, attnacc[fd], 0, 0, 0);
                attnacc[fd] = __builtin_amdgcn_mfma_f32_16x16x32_bf16(a2l, b2h, attnacc[fd], 0, 0, 0);
            }
        }
        __syncthreads();
    }

    // z: reduce over lg lanes (same li => same token n = w*16+li)
    zacc += __shfl_xor(zacc, 16, 64);
    zacc += __shfl_xor(zacc, 32, 64);
    float zn = 1.0f / (zacc + 1e-8f);
    // redistribute: lane needs z for rows n = w*16 + lg*4 + r (held at lane li'=lg*4+r)
    float zr[4];
    #pragma unroll
    for (int r = 0; r < 4; ++r) zr[r] = __shfl(zn, lg * 4 + r, 64);

    #pragma unroll
    for (int fd = 0; fd < 4; ++fd) {
        int d = h * 64 + fd * 16 + li;
        #pragma unroll
        for (int r = 0; r < 4; ++r) {
            int n = n0 + w * 16 + lg * 4 + r;
            attn[((size_t)b * NTOK + n) * 1024 + d] = attnacc[fd][r] * zr[r];
        }
    }
}

// ---------------------------------------------------------------------------
extern "C" void kernel_launch(void* const* d_in, const int* in_sizes, int n_in,
                              void* d_out, int out_size, void* d_ws, size_t ws_size,
                              hipStream_t stream)
{
    const float* x      = (const float*)d_in[0];
    const float* w_qkv  = (const float*)d_in[1];
    const float* proj   = (const float*)d_in[2];
    const float* w_out  = (const float*)d_in[3];
    const float* b_out  = (const float*)d_in[4];
    float* out = (float*)d_out;
    float* ws  = (float*)d_ws;

    if (ws_size < (size_t)WS_FLOATS * sizeof(float)) return;

    float* kvst   = ws + OFF_KV;
    float* ksum   = ws + OFF_KSUM;
    float* attnb  = ws + OFF_ATTN;
    float* kvbuf  = ws + OFF_KVBUF;
    float* qbuf   = ws + OFF_QBUF;
    unsigned short* proj_pre = (unsigned short*)(ws + OFF_PROJPRE);
    unsigned short* kv_pre   = (unsigned short*)(ws + OFF_KVPRE);
    unsigned short* wkv_pre  = (unsigned short*)(ws + OFF_WKVPRE);
    unsigned short* wq_pre   = (unsigned short*)(ws + OFF_WQPRE);
    unsigned short* wout_pre = (unsigned short*)(ws + OFF_WOUTPRE);

    dim3 blk(256);
    zero_kernel<<<1024, blk, 0, stream>>>((float4*)kvst, ZERO_F4);
    preconv_kernel<<<512, blk, 0, stream>>>(w_qkv, H3, 1024, 16, wkv_pre);
    preconv_kernel<<<256, blk, 0, stream>>>(w_qkv, H3, 0, 8, wq_pre);
    projconv_kernel<<<64, blk, 0, stream>>>(proj, proj_pre);

    // phase 1: kv state
    for (int b = 0; b < NB; ++b) {
        mfma_gemm<<<dim3(16, 32), blk, 0, stream>>>(
            x + (size_t)b * NTOK * DIM, wkv_pre, nullptr, kvbuf,
            1024, DIM, 2048, 16, 0);
        kv_kernel<<<dim3(8, 4, 16), blk, 0, stream>>>(kvbuf, proj, kvst, ksum, b);
    }
    kvconv_kernel<<<256, blk, 0, stream>>>(kvst, kv_pre);

    // phase 2: attention
    for (int b = 0; b < NB; ++b) {
        mfma_gemm<<<dim3(8, 32), blk, 0, stream>>>(
            x + (size_t)b * NTOK * DIM, wq_pre, nullptr, qbuf,
            1024, DIM, 1024, 8, 0);
        attn_mfma<<<dim3(64, 16), blk, 0, stream>>>(
            qbuf, proj_pre, kv_pre, ksum, attnb, b);
    }

    // phase 3: output GEMM
    preconv_kernel<<<256, blk, 0, stream>>>(w_out, DIM, 0, 8, wout_pre);
    mfma_gemm<<<dim3(8, 128), blk, 0, stream>>>(
        attnb, wout_pre, b_out, out, 1024, DIM, DIM, 8, 1);
}

// Round 5
// 1120.016 us; speedup vs baseline: 2.2750x; 1.0793x over previous
//
#include <hip/hip_runtime.h>

// LinearPerformerAttention on MI355X — round 5: fully per-batch pipeline,
// all GEMMs via pre-tiled split-bf16 with dual global_load_lds staging.
// B=4, N=4096, DIM=1024, H=16, HD=64, FEAT=256.

#define NTOK 4096
#define NB 4
#define DIM 1024
#define H3 3072
#define FEAT 256

// workspace float offsets (93.4 MB total; 117.5 MB proven available)
#define OFF_PROJPRE 0u             // 262,144 fl
#define OFF_KVPRE   262144u        // 1,048,576 fl
#define OFF_KSUM    1310720u       // 16,384 fl
#define OFF_KVST    1327104u       // 1,048,576 fl
#define OFF_WKV     2375680u       // 2,097,152 fl
#define OFF_WQ      4472832u       // 1,048,576 fl
#define OFF_WOUT    5521408u       // 1,048,576 fl
#define OFF_XPRE    6569984u       // 4,194,304 fl (per-batch, reused)
#define OFF_KVBUF   10764288u      // 8,388,608 fl (per-batch, reused)
#define OFF_QBUF    10764288u      // overlay of kvbuf (dead after kv_kernel)
#define OFF_ATTNPRE 19152896u      // 4,194,304 fl (per-batch, reused)
#define WS_FLOATS   23347200u
#define ZERO_F4     266240u        // (ksum + kvst)/4, zero from OFF_KSUM

typedef short short8 __attribute__((ext_vector_type(8)));
typedef float f32x4  __attribute__((ext_vector_type(4)));
typedef unsigned short us4 __attribute__((ext_vector_type(4)));

__device__ __forceinline__ float elu1f(float v) {
    return v > 0.f ? v + 1.f : __expf(v);
}
__device__ __forceinline__ unsigned short f2bf(float f) {
    unsigned u = __float_as_uint(f);
    u += 0x7fffu + ((u >> 16) & 1u);
    return (unsigned short)(u >> 16);
}
__device__ __forceinline__ float bf2f(unsigned short s) {
    return __uint_as_float((unsigned)s << 16);
}
__device__ __forceinline__ void pack8(const float* f, uint4& ph, uint4& pl) {
    unsigned short hi[8], lo[8];
    #pragma unroll
    for (int j = 0; j < 8; ++j) {
        hi[j] = f2bf(f[j]);
        lo[j] = f2bf(f[j] - bf2f(hi[j]));
    }
    ph.x = (unsigned)hi[0] | ((unsigned)hi[1] << 16);
    ph.y = (unsigned)hi[2] | ((unsigned)hi[3] << 16);
    ph.z = (unsigned)hi[4] | ((unsigned)hi[5] << 16);
    ph.w = (unsigned)hi[6] | ((unsigned)hi[7] << 16);
    pl.x = (unsigned)lo[0] | ((unsigned)lo[1] << 16);
    pl.y = (unsigned)lo[2] | ((unsigned)lo[3] << 16);
    pl.z = (unsigned)lo[4] | ((unsigned)lo[5] << 16);
    pl.w = (unsigned)lo[6] | ((unsigned)lo[7] << 16);
}

__global__ void zero_kernel(float4* p, unsigned n4) {
    for (unsigned i = blockIdx.x * blockDim.x + threadIdx.x; i < n4;
         i += gridDim.x * blockDim.x)
        p[i] = make_float4(0.f, 0.f, 0.f, 0.f);
}

// ---------------------------------------------------------------------------
// A-operand pre-convert: x slice (4096x1024 fp32, ld=1024) -> A-tiled bf16
// hi/lo. Tile = 128 rows x 32 k, t = mt*32 + kt; unit u = kg*128 + row holds
// 8 k-consecutive bf16; hi plane shorts [0,4096), lo [4096,8192).
// grid 1024 = mt*32+kt.
// ---------------------------------------------------------------------------
__global__ __launch_bounds__(256) void aconv_kernel(
    const float* __restrict__ X, unsigned short* __restrict__ pre)
{
    const int t = blockIdx.x;
    const int mt = t >> 5, kt = t & 31;
    const int tid = threadIdx.x;
    #pragma unroll
    for (int i = 0; i < 2; ++i) {
        int u = tid + i * 256;
        int kg = u >> 7, row = u & 127;
        const float* sp = X + (size_t)(mt * 128 + row) * 1024 + kt * 32 + kg * 8;
        float4 v0 = *(const float4*)sp;
        float4 v1 = *(const float4*)(sp + 4);
        float f[8] = {v0.x, v0.y, v0.z, v0.w, v1.x, v1.y, v1.z, v1.w};
        uint4 ph, pl;
        pack8(f, ph, pl);
        unsigned short* dst = pre + (size_t)t * 8192 + (size_t)u * 8;
        *(uint4*)dst = ph;
        *(uint4*)(dst + 4096) = pl;
    }
}

// ---------------------------------------------------------------------------
// Weight pre-convert (round-3 verified): fp32 [K][N] slice -> B-tiled bf16
// hi/lo. Tile 32k x 128n, t = kt*NT + nt; unit = 8 k-consecutive bf16.
// ---------------------------------------------------------------------------
__global__ __launch_bounds__(256) void preconv_kernel(
    const float* __restrict__ W, int ldw, int col_off, int NT,
    unsigned short* __restrict__ pre)
{
    __shared__ float T[32][136];
    const int tt = blockIdx.x;
    const int kt = tt / NT, nt = tt % NT;
    const int tid = threadIdx.x;

    #pragma unroll
    for (int i = 0; i < 4; ++i) {
        int f = tid + i * 256;
        int r = f >> 5, c4 = f & 31;
        float4 v = *(const float4*)&W[(size_t)(kt * 32 + r) * ldw + col_off + nt * 128 + c4 * 4];
        *(float4*)&T[r][c4 * 4] = v;
    }
    __syncthreads();

    #pragma unroll
    for (int half = 0; half < 2; ++half) {
        int u = tid + half * 256;
        int kg = u >> 7, col = u & 127;
        float f[8];
        #pragma unroll
        for (int j = 0; j < 8; ++j) f[j] = T[kg * 8 + j][col];
        uint4 ph, pl;
        pack8(f, ph, pl);
        size_t base = (size_t)tt * 1024;
        *(uint4*)&pre[(base + 0   + kg * 128 + col) * 8] = ph;
        *(uint4*)&pre[(base + 512 + kg * 128 + col) * 8] = pl;
    }
}

// ---------------------------------------------------------------------------
// proj -> A-frag layout (P^T) (round-4 verified). grid 64 = h*4+fc.
// ---------------------------------------------------------------------------
__global__ __launch_bounds__(256) void projconv_kernel(
    const float* __restrict__ proj, unsigned short* __restrict__ pre)
{
    const int blk = blockIdx.x;
    const int h = blk >> 2, fc = blk & 3;
    const int tid = threadIdx.x;
    #pragma unroll
    for (int u0 = 0; u0 < 2; ++u0) {
        int u = tid * 2 + u0;
        int kg = u >> 6, f = u & 63;
        float fv[8];
        #pragma unroll
        for (int j = 0; j < 8; ++j)
            fv[j] = proj[(size_t)(h * 64 + kg * 8 + j) * 256 + fc * 64 + f];
        uint4 ph, pl;
        pack8(fv, ph, pl);
        size_t base = (size_t)blk * 8192;
        *(uint4*)&pre[base + (size_t)(kg * 64 + f) * 8] = ph;
        *(uint4*)&pre[base + 4096 + (size_t)(kg * 64 + f) * 8] = pl;
    }
}

// ---------------------------------------------------------------------------
// kv state -> B-frag layout (round-4 verified), per batch. grid 64 = h*4+fc.
// ---------------------------------------------------------------------------
__global__ __launch_bounds__(256) void kvconv_kernel(
    const float* __restrict__ kvst, unsigned short* __restrict__ pre, int b)
{
    const int blk = blockIdx.x;
    const int h = blk >> 2, fc = blk & 3;
    const int bh = b * 16 + h;
    const int tid = threadIdx.x;
    #pragma unroll
    for (int u0 = 0; u0 < 2; ++u0) {
        int u = tid * 2 + u0;
        int kg = u >> 6, d = u & 63;
        float fv[8];
        #pragma unroll
        for (int j = 0; j < 8; ++j)
            fv[j] = kvst[((size_t)bh * 256 + fc * 64 + kg * 8 + j) * 64 + d];
        uint4 ph, pl;
        pack8(fv, ph, pl);
        size_t base = (size_t)(bh * 4 + fc) * 8192;
        *(uint4*)&pre[base + (size_t)(kg * 64 + d) * 8] = ph;
        *(uint4*)&pre[base + 4096 + (size_t)(kg * 64 + d) * 8] = pl;
    }
}

// ---------------------------------------------------------------------------
// Split-bf16 MFMA GEMM, BOTH operands pre-tiled: C = Apre @ Bpre [+bias].
// 128x128 tile, BK=32, 4 waves; staging = 32 x 1KB global_load_lds chunks
// (waves 0-1: A, waves 2-3: B). Zero VALU in the K-loop. XCD swizzle.
// ---------------------------------------------------------------------------
__global__ __launch_bounds__(256) void mfma_gemm_pre(
    const unsigned short* __restrict__ Apre, const unsigned short* __restrict__ Bpre,
    const float* __restrict__ bias, float* __restrict__ C,
    int K, int ldc, int NT, int hasBias)
{
    __shared__ __align__(16) char smem[32768];
    const int tid = threadIdx.x;
    const int w = tid >> 6, l = tid & 63;
    const int wm = w >> 1, wn = w & 1;
    const int lg = l >> 4, li = l & 15;

    // XCD-aware bijective swizzle (all grids have nwg % 8 == 0)
    const int gx = gridDim.x;
    int bid = blockIdx.y * gx + blockIdx.x;
    int cpx = (gx * gridDim.y) >> 3;
    int nb = (bid & 7) * cpx + (bid >> 3);
    const int mt = nb / gx, nt = nb % gx;
    const int row0 = mt * 128, col0 = nt * 128;
    const int KTA = K >> 5;

    f32x4 acc[4][4] = {};

    for (int kt = 0; kt < KTA; ++kt) {
        const unsigned short* asrc = Apre + ((size_t)mt * KTA + kt) * 8192;
        const unsigned short* bsrc = Bpre + ((size_t)kt * NT + nt) * 8192;
        #pragma unroll
        for (int i = 0; i < 8; ++i) {
            int c = w * 8 + i;   // 0..31, wave-uniform
            const unsigned short* s =
                (c < 16 ? asrc + (size_t)c * 512 : bsrc + (size_t)(c - 16) * 512)
                + (size_t)l * 8;
            char* d = smem + c * 1024;
            __builtin_amdgcn_global_load_lds(
                (const __attribute__((address_space(1))) unsigned int*)s,
                (__attribute__((address_space(3))) unsigned int*)d, 16, 0, 0);
        }
        __syncthreads();

        short8 ah[4], al_[4], bh[4], bl_[4];
        #pragma unroll
        for (int fm = 0; fm < 4; ++fm) {
            int row = wm * 64 + fm * 16 + li;
            ah[fm]  = *(const short8*)(smem +        lg * 2048 + row * 16);
            al_[fm] = *(const short8*)(smem + 8192 + lg * 2048 + row * 16);
        }
        #pragma unroll
        for (int fn = 0; fn < 4; ++fn) {
            int col = wn * 64 + fn * 16 + li;
            bh[fn]  = *(const short8*)(smem + 16384 + lg * 2048 + col * 16);
            bl_[fn] = *(const short8*)(smem + 24576 + lg * 2048 + col * 16);
        }
        #pragma unroll
        for (int fm = 0; fm < 4; ++fm)
            #pragma unroll
            for (int fn = 0; fn < 4; ++fn) {
                acc[fm][fn] = __builtin_amdgcn_mfma_f32_16x16x32_bf16(ah[fm], bh[fn], acc[fm][fn], 0, 0, 0);
                acc[fm][fn] = __builtin_amdgcn_mfma_f32_16x16x32_bf16(ah[fm], bl_[fn], acc[fm][fn], 0, 0, 0);
                acc[fm][fn] = __builtin_amdgcn_mfma_f32_16x16x32_bf16(al_[fm], bh[fn], acc[fm][fn], 0, 0, 0);
            }
        __syncthreads();
    }

    float bv[4];
    #pragma unroll
    for (int fn = 0; fn < 4; ++fn)
        bv[fn] = hasBias ? bias[col0 + wn * 64 + fn * 16 + li] : 0.f;
    #pragma unroll
    for (int fm = 0; fm < 4; ++fm) {
        #pragma unroll
        for (int fn = 0; fn < 4; ++fn) {
            int col = col0 + wn * 64 + fn * 16 + li;
            #pragma unroll
            for (int r = 0; r < 4; ++r) {
                int row = row0 + wm * 64 + fm * 16 + lg * 4 + r;
                C[(size_t)row * ldc + col] = acc[fm][fn][r] + bv[fn];
            }
        }
    }
}

// ---------------------------------------------------------------------------
// kv_kernel (unchanged fp32; next-round MFMA target).
// ---------------------------------------------------------------------------
__global__ __launch_bounds__(256) void kv_kernel(
    const float* __restrict__ kvbuf, const float* __restrict__ proj,
    float* __restrict__ kv, float* __restrict__ ksum, int b)
{
    __shared__ float Kl[64][68];
    __shared__ float Vl[64][64];
    __shared__ float Pl[64][64];
    const int tid = threadIdx.x;
    const int tx = tid & 15, ty = tid >> 4;
    const int ns = blockIdx.x, fc = blockIdx.y, h = blockIdx.z;
    const int bh = b * 16 + h;
    const int f0 = fc * 64;

    #pragma unroll
    for (int l = 0; l < 4; ++l) {
        int f4 = tid + l * 256;
        int kk = f4 >> 4, c4 = f4 & 15;
        *(float4*)&Pl[kk][c4 * 4] =
            *(const float4*)&proj[(size_t)(h * 64 + kk) * 256 + f0 + c4 * 4];
    }
    const float* kbase = kvbuf + h * 64;
    const float* vbase = kvbuf + 1024 + h * 64;

    float kvacc[4][4] = {};
    float ksacc[4] = {};
    __syncthreads();

    for (int t = 0; t < 8; ++t) {
        const int n0 = ns * 512 + t * 64;
        #pragma unroll
        for (int l = 0; l < 4; ++l) {
            int f4 = tid + l * 256;
            int r = f4 >> 4, c4 = f4 & 15;
            *(float4*)&Kl[r][c4 * 4] = *(const float4*)&kbase[(size_t)(n0 + r) * 2048 + c4 * 4];
            *(float4*)&Vl[r][c4 * 4] = *(const float4*)&vbase[(size_t)(n0 + r) * 2048 + c4 * 4];
        }
        __syncthreads();

        float kp[4][4] = {};
        #pragma unroll
        for (int kk0 = 0; kk0 < 64; kk0 += 4) {
            float a[4][4], bb[4][4];
            #pragma unroll
            for (int i = 0; i < 4; ++i)
                *(float4*)&a[i][0] = *(const float4*)&Kl[ty * 4 + i][kk0];
            #pragma unroll
            for (int kx = 0; kx < 4; ++kx)
                *(float4*)&bb[kx][0] = *(const float4*)&Pl[kk0 + kx][tx * 4];
            #pragma unroll
            for (int i = 0; i < 4; ++i)
                #pragma unroll
                for (int kx = 0; kx < 4; ++kx) {
                    float av = a[i][kx];
                    #pragma unroll
                    for (int j = 0; j < 4; ++j) kp[i][j] += av * bb[kx][j];
                }
        }
        #pragma unroll
        for (int i = 0; i < 4; ++i)
            #pragma unroll
            for (int j = 0; j < 4; ++j) kp[i][j] = elu1f(kp[i][j]);

        __syncthreads();
        #pragma unroll
        for (int i = 0; i < 4; ++i) {
            float4 v; v.x = kp[i][0]; v.y = kp[i][1]; v.z = kp[i][2]; v.w = kp[i][3];
            *(float4*)&Kl[ty * 4 + i][tx * 4] = v;
        }
        __syncthreads();

        #pragma unroll
        for (int nn = 0; nn < 64; ++nn) {
            float a[4], bv[4];
            *(float4*)&a[0]  = *(const float4*)&Kl[nn][ty * 4];
            *(float4*)&bv[0] = *(const float4*)&Vl[nn][tx * 4];
            #pragma unroll
            for (int i = 0; i < 4; ++i) ksacc[i] += a[i];
            #pragma unroll
            for (int i = 0; i < 4; ++i)
                #pragma unroll
                for (int j = 0; j < 4; ++j) kvacc[i][j] += a[i] * bv[j];
        }
        __syncthreads();
    }

    float* kvdst = kv + ((size_t)bh * 256 + f0) * 64;
    #pragma unroll
    for (int i = 0; i < 4; ++i)
        #pragma unroll
        for (int j = 0; j < 4; ++j)
            atomicAdd(&kvdst[(size_t)(ty * 4 + i) * 64 + tx * 4 + j], kvacc[i][j]);
    if (tx == 0) {
        #pragma unroll
        for (int i = 0; i < 4; ++i)
            atomicAdd(&ksum[(size_t)bh * 256 + f0 + ty * 4 + i], ksacc[i]);
    }
}

// ---------------------------------------------------------------------------
// attn_mfma (round-4 verified core): per (64-token tile, head) of batch b.
// NEW epilogue: LDS transpose -> write output directly in A-tiled bf16 hi/lo
// layout (attnpre) so the out-GEMM uses the pure global_load_lds path.
// grid (64, 16); 256 thr = 4 waves.
// ---------------------------------------------------------------------------
__global__ __launch_bounds__(256) void attn_mfma(
    const float* __restrict__ qbuf, const unsigned short* __restrict__ projpre,
    const unsigned short* __restrict__ kvpre, const float* __restrict__ ksum,
    unsigned short* __restrict__ attnpre, int b)
{
    __shared__ __align__(16) char smem[49152];   // QP 16K | BP 16K | BKV 16K
    char* QP  = smem;
    char* BP  = smem + 16384;
    char* BKV = smem + 32768;
    const int tid = threadIdx.x;
    const int w = tid >> 6, l = tid & 63;
    const int lg = l >> 4, li = l & 15;
    const int nt = blockIdx.x, h = blockIdx.y;
    const int bh = b * 16 + h;
    const int n0 = nt * 64;

    // q B-frags -> registers
    short8 qh[2], ql[2];
    {
        const float* qrow = qbuf + (size_t)(n0 + w * 16 + li) * 1024 + h * 64;
        #pragma unroll
        for (int ks = 0; ks < 2; ++ks) {
            int kc = (ks * 4 + lg) * 8;
            float4 v0 = *(const float4*)&qrow[kc];
            float4 v1 = *(const float4*)&qrow[kc + 4];
            float f[8] = {v0.x, v0.y, v0.z, v0.w, v1.x, v1.y, v1.z, v1.w};
            short8 qhv, qlv;
            #pragma unroll
            for (int j = 0; j < 8; ++j) {
                unsigned short hv = f2bf(f[j]);
                qhv[j] = (short)hv;
                qlv[j] = (short)f2bf(f[j] - bf2f(hv));
            }
            qh[ks] = qhv; ql[ks] = qlv;
        }
    }

    f32x4 attnacc[4] = {};
    float zacc = 0.f;

    for (int fc = 0; fc < 4; ++fc) {
        const unsigned short* psrc = projpre + (size_t)(h * 4 + fc) * 8192;
        const unsigned short* csrc = kvpre + (size_t)(bh * 4 + fc) * 8192;
        #pragma unroll
        for (int i = 0; i < 4; ++i) {
            int u = tid + i * 256;
            __builtin_amdgcn_global_load_lds(
                (const __attribute__((address_space(1))) unsigned int*)(psrc + (size_t)u * 8),
                (__attribute__((address_space(3))) unsigned int*)(BP + u * 16), 16, 0, 0);
            __builtin_amdgcn_global_load_lds(
                (const __attribute__((address_space(1))) unsigned int*)(csrc + (size_t)u * 8),
                (__attribute__((address_space(3))) unsigned int*)(BKV + u * 16), 16, 0, 0);
        }
        __syncthreads();

        // qp-MFMA: D'[f][n]
        f32x4 accp[4] = {};
        #pragma unroll
        for (int ks = 0; ks < 2; ++ks) {
            #pragma unroll
            for (int ff = 0; ff < 4; ++ff) {
                int f = ff * 16 + li;
                short8 ah = *(const short8*)(BP +        (ks * 4 + lg) * 1024 + f * 16);
                short8 al = *(const short8*)(BP + 8192 + (ks * 4 + lg) * 1024 + f * 16);
                accp[ff] = __builtin_amdgcn_mfma_f32_16x16x32_bf16(ah, qh[ks], accp[ff], 0, 0, 0);
                accp[ff] = __builtin_amdgcn_mfma_f32_16x16x32_bf16(ah, ql[ks], accp[ff], 0, 0, 0);
                accp[ff] = __builtin_amdgcn_mfma_f32_16x16x32_bf16(al, qh[ks], accp[ff], 0, 0, 0);
            }
        }

        // elu + z + bf16 hi/lo pack -> QP (A-layout)
        #pragma unroll
        for (int ff = 0; ff < 4; ++ff) {
            float4 ks4 = *(const float4*)&ksum[(size_t)bh * 256 + fc * 64 + ff * 16 + lg * 4];
            float kse[4] = {ks4.x, ks4.y, ks4.z, ks4.w};
            us4 h4, l4;
            #pragma unroll
            for (int r = 0; r < 4; ++r) {
                float v = elu1f(accp[ff][r]);
                zacc += v * kse[r];
                unsigned short hv = f2bf(v);
                h4[r] = hv;
                l4[r] = f2bf(v - bf2f(hv));
            }
            int boff = (ff * 2 + (lg >> 1)) * 1024 + (w * 16 + li) * 16 + (lg & 1) * 8;
            *(us4*)(QP + boff) = h4;
            *(us4*)(QP + 8192 + boff) = l4;
        }
        __syncthreads();

        // attn-MFMA: D2[n][d] += qp @ kv_chunk
        #pragma unroll
        for (int ks = 0; ks < 2; ++ks) {
            short8 a2h = *(const short8*)(QP +        (ks * 4 + lg) * 1024 + (w * 16 + li) * 16);
            short8 a2l = *(const short8*)(QP + 8192 + (ks * 4 + lg) * 1024 + (w * 16 + li) * 16);
            #pragma unroll
            for (int fd = 0; fd < 4; ++fd) {
                int d = fd * 16 + li;
                short8 b2h = *(const short8*)(BKV +        (ks * 4 + lg) * 1024 + d * 16);
                short8 b2l = *(const short8*)(BKV + 8192 + (ks * 4 + lg) * 1024 + d * 16);
                attnacc[fd] = __builtin_amdgcn_mfma_f32_16x16x32_bf16(a2h, b2h, attnacc[fd], 0, 0, 0);
                attnacc[fd] = __builtin_amdgcn_mfma_f32_16x16x32_bf16(a2h, b2l, attnacc[fd], 0, 0, 0);
                attnacc[fd] = __builtin_amdgcn_mfma_f32_16x16x32_bf16(a2l, b2h, attnacc[fd], 0, 0, 0);
            }
        }
        __syncthreads();
    }

    // z reduce + redistribute
    zacc += __shfl_xor(zacc, 16, 64);
    zacc += __shfl_xor(zacc, 32, 64);
    float zn = 1.0f / (zacc + 1e-8f);
    float zr[4];
    #pragma unroll
    for (int r = 0; r < 4; ++r) zr[r] = __shfl(zn, lg * 4 + r, 64);

    // epilogue: scaled result -> LDS fp32 [64][68] -> pre-tiled bf16 hi/lo
    float* Sb = (float*)smem;
    #pragma unroll
    for (int fd = 0; fd < 4; ++fd) {
        int d = fd * 16 + li;
        #pragma unroll
        for (int r = 0; r < 4; ++r) {
            int n = w * 16 + lg * 4 + r;
            Sb[n * 68 + d] = attnacc[fd][r] * zr[r];
        }
    }
    __syncthreads();

    const int mt = nt >> 1, rhalf = (nt & 1) * 64;
    #pragma unroll
    for (int i = 0; i < 2; ++i) {
        int u = tid + i * 256;             // 512 units: r64(64) x {ktL(2) x kg(4)}
        int r64 = u >> 3, c8 = u & 7;
        int ktL = c8 >> 2, kg = c8 & 3;
        const float* sp = Sb + r64 * 68 + ktL * 32 + kg * 8;
        float f[8];
        #pragma unroll
        for (int j = 0; j < 8; ++j) f[j] = sp[j];
        uint4 ph, pl;
        pack8(f, ph, pl);
        size_t t = (size_t)mt * 32 + (h * 2 + ktL);
        unsigned short* dst = attnpre + t * 8192 + (size_t)(kg * 128 + rhalf + r64) * 8;
        *(uint4*)dst = ph;
        *(uint4*)(dst + 4096) = pl;
    }
}

// ---------------------------------------------------------------------------
extern "C" void kernel_launch(void* const* d_in, const int* in_sizes, int n_in,
                              void* d_out, int out_size, void* d_ws, size_t ws_size,
                              hipStream_t stream)
{
    const float* x      = (const float*)d_in[0];
    const float* w_qkv  = (const float*)d_in[1];
    const float* proj   = (const float*)d_in[2];
    const float* w_out  = (const float*)d_in[3];
    const float* b_out  = (const float*)d_in[4];
    float* out = (float*)d_out;
    float* ws  = (float*)d_ws;

    if (ws_size < (size_t)WS_FLOATS * sizeof(float)) return;

    unsigned short* proj_pre = (unsigned short*)(ws + OFF_PROJPRE);
    unsigned short* kv_pre   = (unsigned short*)(ws + OFF_KVPRE);
    float* ksum  = ws + OFF_KSUM;
    float* kvst  = ws + OFF_KVST;
    unsigned short* wkv_pre  = (unsigned short*)(ws + OFF_WKV);
    unsigned short* wq_pre   = (unsigned short*)(ws + OFF_WQ);
    unsigned short* wout_pre = (unsigned short*)(ws + OFF_WOUT);
    unsigned short* xpre     = (unsigned short*)(ws + OFF_XPRE);
    float* kvbuf = ws + OFF_KVBUF;
    float* qbuf  = ws + OFF_QBUF;
    unsigned short* attnpre  = (unsigned short*)(ws + OFF_ATTNPRE);

    dim3 blk(256);
    zero_kernel<<<1024, blk, 0, stream>>>((float4*)(ws + OFF_KSUM), ZERO_F4);
    preconv_kernel<<<512, blk, 0, stream>>>(w_qkv, H3, 1024, 16, wkv_pre);
    preconv_kernel<<<256, blk, 0, stream>>>(w_qkv, H3, 0, 8, wq_pre);
    preconv_kernel<<<256, blk, 0, stream>>>(w_out, DIM, 0, 8, wout_pre);
    projconv_kernel<<<64, blk, 0, stream>>>(proj, proj_pre);

    for (int b = 0; b < NB; ++b) {
        const float* xb = x + (size_t)b * NTOK * DIM;
        // x_b -> pre-tiled bf16 hi/lo
        aconv_kernel<<<1024, blk, 0, stream>>>(xb, xpre);
        // k,v = x_b @ Wkv
        mfma_gemm_pre<<<dim3(16, 32), blk, 0, stream>>>(
            xpre, wkv_pre, nullptr, kvbuf, 1024, 2048, 16, 0);
        // kv state + ksum for batch b
        kv_kernel<<<dim3(8, 4, 16), blk, 0, stream>>>(kvbuf, proj, kvst, ksum, b);
        kvconv_kernel<<<64, blk, 0, stream>>>(kvst, kv_pre, b);
        // q = x_b @ Wq  (qbuf overlays kvbuf region — kvbuf dead now)
        mfma_gemm_pre<<<dim3(8, 32), blk, 0, stream>>>(
            xpre, wq_pre, nullptr, qbuf, 1024, 1024, 8, 0);
        // attention -> pre-tiled attnpre
        attn_mfma<<<dim3(64, 16), blk, 0, stream>>>(
            qbuf, proj_pre, kv_pre, ksum, attnpre, b);
        // out rows for batch b
        mfma_gemm_pre<<<dim3(8, 32), blk, 0, stream>>>(
            attnpre, wout_pre, b_out, out + (size_t)b * NTOK * DIM, 1024, 1024, 8, 1);
    }
}

// Round 6
// 1030.099 us; speedup vs baseline: 2.4736x; 1.0873x over previous
//
#include <hip/hip_runtime.h>

// LinearPerformerAttention on MI355X — round 6: kv phase on MFMA (kv_mfma
// replaces fp32 kv_kernel). Everything else identical to passing round 5.
// B=4, N=4096, DIM=1024, H=16, HD=64, FEAT=256.

#define NTOK 4096
#define NB 4
#define DIM 1024
#define H3 3072
#define FEAT 256

// workspace float offsets (93.4 MB total; 117.5 MB proven available)
#define OFF_PROJPRE 0u             // 262,144 fl
#define OFF_KVPRE   262144u        // 1,048,576 fl
#define OFF_KSUM    1310720u       // 16,384 fl
#define OFF_KVST    1327104u       // 1,048,576 fl
#define OFF_WKV     2375680u       // 2,097,152 fl
#define OFF_WQ      4472832u       // 1,048,576 fl
#define OFF_WOUT    5521408u       // 1,048,576 fl
#define OFF_XPRE    6569984u       // 4,194,304 fl (per-batch, reused)
#define OFF_KVBUF   10764288u      // 8,388,608 fl (per-batch, reused)
#define OFF_QBUF    10764288u      // overlay of kvbuf (dead after kv phase)
#define OFF_ATTNPRE 19152896u      // 4,194,304 fl (per-batch, reused)
#define WS_FLOATS   23347200u
#define ZERO_F4     266240u        // (ksum + kvst)/4, zero from OFF_KSUM

typedef short short8 __attribute__((ext_vector_type(8)));
typedef float f32x4  __attribute__((ext_vector_type(4)));
typedef unsigned short us4 __attribute__((ext_vector_type(4)));

__device__ __forceinline__ float elu1f(float v) {
    return v > 0.f ? v + 1.f : __expf(v);
}
__device__ __forceinline__ unsigned short f2bf(float f) {
    unsigned u = __float_as_uint(f);
    u += 0x7fffu + ((u >> 16) & 1u);
    return (unsigned short)(u >> 16);
}
__device__ __forceinline__ float bf2f(unsigned short s) {
    return __uint_as_float((unsigned)s << 16);
}
__device__ __forceinline__ void pack8(const float* f, uint4& ph, uint4& pl) {
    unsigned short hi[8], lo[8];
    #pragma unroll
    for (int j = 0; j < 8; ++j) {
        hi[j] = f2bf(f[j]);
        lo[j] = f2bf(f[j] - bf2f(hi[j]));
    }
    ph.x = (unsigned)hi[0] | ((unsigned)hi[1] << 16);
    ph.y = (unsigned)hi[2] | ((unsigned)hi[3] << 16);
    ph.z = (unsigned)hi[4] | ((unsigned)hi[5] << 16);
    ph.w = (unsigned)hi[6] | ((unsigned)hi[7] << 16);
    pl.x = (unsigned)lo[0] | ((unsigned)lo[1] << 16);
    pl.y = (unsigned)lo[2] | ((unsigned)lo[3] << 16);
    pl.z = (unsigned)lo[4] | ((unsigned)lo[5] << 16);
    pl.w = (unsigned)lo[6] | ((unsigned)lo[7] << 16);
}

__global__ void zero_kernel(float4* p, unsigned n4) {
    for (unsigned i = blockIdx.x * blockDim.x + threadIdx.x; i < n4;
         i += gridDim.x * blockDim.x)
        p[i] = make_float4(0.f, 0.f, 0.f, 0.f);
}

// ---------------------------------------------------------------------------
// A-operand pre-convert (round-5 verified). grid 1024 = mt*32+kt.
// ---------------------------------------------------------------------------
__global__ __launch_bounds__(256) void aconv_kernel(
    const float* __restrict__ X, unsigned short* __restrict__ pre)
{
    const int t = blockIdx.x;
    const int mt = t >> 5, kt = t & 31;
    const int tid = threadIdx.x;
    #pragma unroll
    for (int i = 0; i < 2; ++i) {
        int u = tid + i * 256;
        int kg = u >> 7, row = u & 127;
        const float* sp = X + (size_t)(mt * 128 + row) * 1024 + kt * 32 + kg * 8;
        float4 v0 = *(const float4*)sp;
        float4 v1 = *(const float4*)(sp + 4);
        float f[8] = {v0.x, v0.y, v0.z, v0.w, v1.x, v1.y, v1.z, v1.w};
        uint4 ph, pl;
        pack8(f, ph, pl);
        unsigned short* dst = pre + (size_t)t * 8192 + (size_t)u * 8;
        *(uint4*)dst = ph;
        *(uint4*)(dst + 4096) = pl;
    }
}

// ---------------------------------------------------------------------------
// Weight pre-convert (round-3 verified).
// ---------------------------------------------------------------------------
__global__ __launch_bounds__(256) void preconv_kernel(
    const float* __restrict__ W, int ldw, int col_off, int NT,
    unsigned short* __restrict__ pre)
{
    __shared__ float T[32][136];
    const int tt = blockIdx.x;
    const int kt = tt / NT, nt = tt % NT;
    const int tid = threadIdx.x;

    #pragma unroll
    for (int i = 0; i < 4; ++i) {
        int f = tid + i * 256;
        int r = f >> 5, c4 = f & 31;
        float4 v = *(const float4*)&W[(size_t)(kt * 32 + r) * ldw + col_off + nt * 128 + c4 * 4];
        *(float4*)&T[r][c4 * 4] = v;
    }
    __syncthreads();

    #pragma unroll
    for (int half = 0; half < 2; ++half) {
        int u = tid + half * 256;
        int kg = u >> 7, col = u & 127;
        float f[8];
        #pragma unroll
        for (int j = 0; j < 8; ++j) f[j] = T[kg * 8 + j][col];
        uint4 ph, pl;
        pack8(f, ph, pl);
        size_t base = (size_t)tt * 1024;
        *(uint4*)&pre[(base + 0   + kg * 128 + col) * 8] = ph;
        *(uint4*)&pre[(base + 512 + kg * 128 + col) * 8] = pl;
    }
}

// ---------------------------------------------------------------------------
// proj -> frag layout (unit = 8 consecutive hd for f; serves as A-frags for
// attn_mfma AND B-frags for kv_mfma — identical memory layout). grid 64.
// ---------------------------------------------------------------------------
__global__ __launch_bounds__(256) void projconv_kernel(
    const float* __restrict__ proj, unsigned short* __restrict__ pre)
{
    const int blk = blockIdx.x;
    const int h = blk >> 2, fc = blk & 3;
    const int tid = threadIdx.x;
    #pragma unroll
    for (int u0 = 0; u0 < 2; ++u0) {
        int u = tid * 2 + u0;
        int kg = u >> 6, f = u & 63;
        float fv[8];
        #pragma unroll
        for (int j = 0; j < 8; ++j)
            fv[j] = proj[(size_t)(h * 64 + kg * 8 + j) * 256 + fc * 64 + f];
        uint4 ph, pl;
        pack8(fv, ph, pl);
        size_t base = (size_t)blk * 8192;
        *(uint4*)&pre[base + (size_t)(kg * 64 + f) * 8] = ph;
        *(uint4*)&pre[base + 4096 + (size_t)(kg * 64 + f) * 8] = pl;
    }
}

// ---------------------------------------------------------------------------
// kv state -> B-frag layout (round-4 verified), per batch. grid 64.
// ---------------------------------------------------------------------------
__global__ __launch_bounds__(256) void kvconv_kernel(
    const float* __restrict__ kvst, unsigned short* __restrict__ pre, int b)
{
    const int blk = blockIdx.x;
    const int h = blk >> 2, fc = blk & 3;
    const int bh = b * 16 + h;
    const int tid = threadIdx.x;
    #pragma unroll
    for (int u0 = 0; u0 < 2; ++u0) {
        int u = tid * 2 + u0;
        int kg = u >> 6, d = u & 63;
        float fv[8];
        #pragma unroll
        for (int j = 0; j < 8; ++j)
            fv[j] = kvst[((size_t)bh * 256 + fc * 64 + kg * 8 + j) * 64 + d];
        uint4 ph, pl;
        pack8(fv, ph, pl);
        size_t base = (size_t)(bh * 4 + fc) * 8192;
        *(uint4*)&pre[base + (size_t)(kg * 64 + d) * 8] = ph;
        *(uint4*)&pre[base + 4096 + (size_t)(kg * 64 + d) * 8] = pl;
    }
}

// ---------------------------------------------------------------------------
// Split-bf16 MFMA GEMM, both operands pre-tiled (round-5 verified).
// ---------------------------------------------------------------------------
__global__ __launch_bounds__(256) void mfma_gemm_pre(
    const unsigned short* __restrict__ Apre, const unsigned short* __restrict__ Bpre,
    const float* __restrict__ bias, float* __restrict__ C,
    int K, int ldc, int NT, int hasBias)
{
    __shared__ __align__(16) char smem[32768];
    const int tid = threadIdx.x;
    const int w = tid >> 6, l = tid & 63;
    const int wm = w >> 1, wn = w & 1;
    const int lg = l >> 4, li = l & 15;

    const int gx = gridDim.x;
    int bid = blockIdx.y * gx + blockIdx.x;
    int cpx = (gx * gridDim.y) >> 3;
    int nb = (bid & 7) * cpx + (bid >> 3);
    const int mt = nb / gx, nt = nb % gx;
    const int row0 = mt * 128, col0 = nt * 128;
    const int KTA = K >> 5;

    f32x4 acc[4][4] = {};

    for (int kt = 0; kt < KTA; ++kt) {
        const unsigned short* asrc = Apre + ((size_t)mt * KTA + kt) * 8192;
        const unsigned short* bsrc = Bpre + ((size_t)kt * NT + nt) * 8192;
        #pragma unroll
        for (int i = 0; i < 8; ++i) {
            int c = w * 8 + i;
            const unsigned short* s =
                (c < 16 ? asrc + (size_t)c * 512 : bsrc + (size_t)(c - 16) * 512)
                + (size_t)l * 8;
            char* d = smem + c * 1024;
            __builtin_amdgcn_global_load_lds(
                (const __attribute__((address_space(1))) unsigned int*)s,
                (__attribute__((address_space(3))) unsigned int*)d, 16, 0, 0);
        }
        __syncthreads();

        short8 ah[4], al_[4], bh[4], bl_[4];
        #pragma unroll
        for (int fm = 0; fm < 4; ++fm) {
            int row = wm * 64 + fm * 16 + li;
            ah[fm]  = *(const short8*)(smem +        lg * 2048 + row * 16);
            al_[fm] = *(const short8*)(smem + 8192 + lg * 2048 + row * 16);
        }
        #pragma unroll
        for (int fn = 0; fn < 4; ++fn) {
            int col = wn * 64 + fn * 16 + li;
            bh[fn]  = *(const short8*)(smem + 16384 + lg * 2048 + col * 16);
            bl_[fn] = *(const short8*)(smem + 24576 + lg * 2048 + col * 16);
        }
        #pragma unroll
        for (int fm = 0; fm < 4; ++fm)
            #pragma unroll
            for (int fn = 0; fn < 4; ++fn) {
                acc[fm][fn] = __builtin_amdgcn_mfma_f32_16x16x32_bf16(ah[fm], bh[fn], acc[fm][fn], 0, 0, 0);
                acc[fm][fn] = __builtin_amdgcn_mfma_f32_16x16x32_bf16(ah[fm], bl_[fn], acc[fm][fn], 0, 0, 0);
                acc[fm][fn] = __builtin_amdgcn_mfma_f32_16x16x32_bf16(al_[fm], bh[fn], acc[fm][fn], 0, 0, 0);
            }
        __syncthreads();
    }

    float bv[4];
    #pragma unroll
    for (int fn = 0; fn < 4; ++fn)
        bv[fn] = hasBias ? bias[col0 + wn * 64 + fn * 16 + li] : 0.f;
    #pragma unroll
    for (int fm = 0; fm < 4; ++fm) {
        #pragma unroll
        for (int fn = 0; fn < 4; ++fn) {
            int col = col0 + wn * 64 + fn * 16 + li;
            #pragma unroll
            for (int r = 0; r < 4; ++r) {
                int row = row0 + wm * 64 + fm * 16 + lg * 4 + r;
                C[(size_t)row * ldc + col] = acc[fm][fn][r] + bv[fn];
            }
        }
    }
}

// ---------------------------------------------------------------------------
// kv_mfma: per (ns 128-token slice, head h) of batch b, 4 chunks of 32 n.
// Wave w owns f-slice w*64: MFMA-1 D1[n][f] = K @ P (proj B-frags in regs,
// loop-invariant); elu + ksum on exact fp32; kp us4-packed to wave-private
// A-layout LDS; MFMA-2 D2[f][d] += kp @ V (V cooperatively transposed+
// converted to B-layout). Split-bf16 3-product everywhere. atomics commit.
// grid (32, 16); 256 thr = 4 waves. LDS 48KB.
// ---------------------------------------------------------------------------
__global__ __launch_bounds__(256) void kv_mfma(
    const float* __restrict__ kvbuf, const unsigned short* __restrict__ projpre,
    float* __restrict__ kv, float* __restrict__ ksum, int b)
{
    __shared__ __align__(16) char smem[49152];   // KA 8K | VB 8K | KP 4x8K (Vl fp32 transient in KP)
    const int tid = threadIdx.x;
    const int w = tid >> 6, l = tid & 63;
    const int lg = l >> 4, li = l & 15;
    const int ns = blockIdx.x, h = blockIdx.y;
    const int bh = b * 16 + h;

    // proj B-frags for this wave's f-slice (fc = w): loop-invariant registers
    const unsigned short* pbase = projpre + (size_t)(h * 4 + w) * 8192;
    short8 pjh[4][2], pjl[4][2];
    #pragma unroll
    for (int ff = 0; ff < 4; ++ff)
        #pragma unroll
        for (int ks = 0; ks < 2; ++ks) {
            int kg = ks * 4 + lg;
            pjh[ff][ks] = *(const short8*)&pbase[(size_t)(kg * 64 + ff * 16 + li) * 8];
            pjl[ff][ks] = *(const short8*)&pbase[4096 + (size_t)(kg * 64 + ff * 16 + li) * 8];
        }

    f32x4 acc2[4][4] = {};
    float ksacc[4] = {};
    float* Vl = (float*)(smem + 16384);          // [32][68] fp32 transient
    char* KP = smem + 16384 + w * 8192;          // wave-private kp buffer

    for (int ch = 0; ch < 4; ++ch) {
        const int n0 = ns * 128 + ch * 32;
        // --- stage K -> KA (split-bf16, unit = row n, 8 consec hd) ---
        {
            int kg = tid >> 5, n = tid & 31;
            const float* sp = kvbuf + (size_t)(n0 + n) * 2048 + h * 64 + kg * 8;
            float4 v0 = *(const float4*)sp;
            float4 v1 = *(const float4*)(sp + 4);
            float f[8] = {v0.x, v0.y, v0.z, v0.w, v1.x, v1.y, v1.z, v1.w};
            uint4 ph, pl;
            pack8(f, ph, pl);
            *(uint4*)(smem + kg * 512 + n * 16) = ph;
            *(uint4*)(smem + 4096 + kg * 512 + n * 16) = pl;
        }
        // --- stage V -> Vl fp32 [32][68] ---
        #pragma unroll
        for (int i = 0; i < 2; ++i) {
            int idx = tid + i * 256;
            int n = idx >> 4, d4 = idx & 15;
            float4 v = *(const float4*)&kvbuf[(size_t)(n0 + n) * 2048 + 1024 + h * 64 + d4 * 4];
            *(float4*)&Vl[n * 68 + d4 * 4] = v;
        }
        __syncthreads();
        // --- Vl -> VB (split-bf16, unit = col d, 8 consec n); conflict-free ---
        {
            int d = l;                            // nu == w (wave-uniform)
            float f[8];
            #pragma unroll
            for (int j = 0; j < 8; ++j) f[j] = Vl[(w * 8 + j) * 68 + d];
            uint4 ph, pl;
            pack8(f, ph, pl);
            *(uint4*)(smem + 8192 + w * 1024 + d * 16) = ph;
            *(uint4*)(smem + 12288 + w * 1024 + d * 16) = pl;
        }
        __syncthreads();   // KA+VB ready; Vl (KP region) free

        // --- MFMA-1: D1[n 32][f 64-slice] = K @ P ---
        f32x4 accp[2][4] = {};
        #pragma unroll
        for (int ks = 0; ks < 2; ++ks) {
            int kg = ks * 4 + lg;
            #pragma unroll
            for (int mm = 0; mm < 2; ++mm) {
                short8 kh = *(const short8*)(smem + kg * 512 + (mm * 16 + li) * 16);
                short8 kl = *(const short8*)(smem + 4096 + kg * 512 + (mm * 16 + li) * 16);
                #pragma unroll
                for (int ff = 0; ff < 4; ++ff) {
                    accp[mm][ff] = __builtin_amdgcn_mfma_f32_16x16x32_bf16(kh, pjh[ff][ks], accp[mm][ff], 0, 0, 0);
                    accp[mm][ff] = __builtin_amdgcn_mfma_f32_16x16x32_bf16(kh, pjl[ff][ks], accp[mm][ff], 0, 0, 0);
                    accp[mm][ff] = __builtin_amdgcn_mfma_f32_16x16x32_bf16(kl, pjh[ff][ks], accp[mm][ff], 0, 0, 0);
                }
            }
        }

        // --- elu + ksum + pack kp -> KP (A-layout: unit = row f, 8 consec n) ---
        #pragma unroll
        for (int mm = 0; mm < 2; ++mm)
            #pragma unroll
            for (int ff = 0; ff < 4; ++ff) {
                us4 h4, l4;
                #pragma unroll
                for (int r = 0; r < 4; ++r) {
                    float v = elu1f(accp[mm][ff][r]);
                    ksacc[ff] += v;
                    unsigned short hv = f2bf(v);
                    h4[r] = hv;
                    l4[r] = f2bf(v - bf2f(hv));
                }
                int u = mm * 2 + (lg >> 1);       // n-unit: n = mm*16+lg*4+r
                int boff = u * 1024 + (ff * 16 + li) * 16 + (lg & 1) * 8;
                *(us4*)(KP + boff) = h4;
                *(us4*)(KP + 4096 + boff) = l4;
            }
        __syncthreads();   // KP visible to own wave's ds_reads (ordering)

        // --- MFMA-2: D2[f][d] += kp @ V (k = 32) ---
        #pragma unroll
        for (int fm = 0; fm < 4; ++fm) {
            short8 a2h = *(const short8*)(KP +        lg * 1024 + (fm * 16 + li) * 16);
            short8 a2l = *(const short8*)(KP + 4096 + lg * 1024 + (fm * 16 + li) * 16);
            #pragma unroll
            for (int fd = 0; fd < 4; ++fd) {
                short8 b2h = *(const short8*)(smem + 8192  + lg * 1024 + (fd * 16 + li) * 16);
                short8 b2l = *(const short8*)(smem + 12288 + lg * 1024 + (fd * 16 + li) * 16);
                acc2[fm][fd] = __builtin_amdgcn_mfma_f32_16x16x32_bf16(a2h, b2h, acc2[fm][fd], 0, 0, 0);
                acc2[fm][fd] = __builtin_amdgcn_mfma_f32_16x16x32_bf16(a2h, b2l, acc2[fm][fd], 0, 0, 0);
                acc2[fm][fd] = __builtin_amdgcn_mfma_f32_16x16x32_bf16(a2l, b2h, acc2[fm][fd], 0, 0, 0);
            }
        }
        __syncthreads();   // all reads done before next chunk's staging
    }

    // --- commit: kv atomics (wave f-slice) + ksum ---
    float* kvdst = kv + ((size_t)bh * 256 + w * 64) * 64;
    #pragma unroll
    for (int fm = 0; fm < 4; ++fm)
        #pragma unroll
        for (int fd = 0; fd < 4; ++fd)
            #pragma unroll
            for (int r = 0; r < 4; ++r)
                atomicAdd(&kvdst[(size_t)(fm * 16 + lg * 4 + r) * 64 + fd * 16 + li],
                          acc2[fm][fd][r]);
    #pragma unroll
    for (int ff = 0; ff < 4; ++ff) {
        float s = ksacc[ff];
        s += __shfl_xor(s, 16, 64);
        s += __shfl_xor(s, 32, 64);
        if (lg == 0)
            atomicAdd(&ksum[(size_t)bh * 256 + w * 64 + ff * 16 + li], s);
    }
}

// ---------------------------------------------------------------------------
// attn_mfma (round-5 verified, unchanged).
// ---------------------------------------------------------------------------
__global__ __launch_bounds__(256) void attn_mfma(
    const float* __restrict__ qbuf, const unsigned short* __restrict__ projpre,
    const unsigned short* __restrict__ kvpre, const float* __restrict__ ksum,
    unsigned short* __restrict__ attnpre, int b)
{
    __shared__ __align__(16) char smem[49152];
    char* QP  = smem;
    char* BP  = smem + 16384;
    char* BKV = smem + 32768;
    const int tid = threadIdx.x;
    const int w = tid >> 6, l = tid & 63;
    const int lg = l >> 4, li = l & 15;
    const int nt = blockIdx.x, h = blockIdx.y;
    const int bh = b * 16 + h;
    const int n0 = nt * 64;

    short8 qh[2], ql[2];
    {
        const float* qrow = qbuf + (size_t)(n0 + w * 16 + li) * 1024 + h * 64;
        #pragma unroll
        for (int ks = 0; ks < 2; ++ks) {
            int kc = (ks * 4 + lg) * 8;
            float4 v0 = *(const float4*)&qrow[kc];
            float4 v1 = *(const float4*)&qrow[kc + 4];
            float f[8] = {v0.x, v0.y, v0.z, v0.w, v1.x, v1.y, v1.z, v1.w};
            short8 qhv, qlv;
            #pragma unroll
            for (int j = 0; j < 8; ++j) {
                unsigned short hv = f2bf(f[j]);
                qhv[j] = (short)hv;
                qlv[j] = (short)f2bf(f[j] - bf2f(hv));
            }
            qh[ks] = qhv; ql[ks] = qlv;
        }
    }

    f32x4 attnacc[4] = {};
    float zacc = 0.f;

    for (int fc = 0; fc < 4; ++fc) {
        const unsigned short* psrc = projpre + (size_t)(h * 4 + fc) * 8192;
        const unsigned short* csrc = kvpre + (size_t)(bh * 4 + fc) * 8192;
        #pragma unroll
        for (int i = 0; i < 4; ++i) {
            int u = tid + i * 256;
            __builtin_amdgcn_global_load_lds(
                (const __attribute__((address_space(1))) unsigned int*)(psrc + (size_t)u * 8),
                (__attribute__((address_space(3))) unsigned int*)(BP + u * 16), 16, 0, 0);
            __builtin_amdgcn_global_load_lds(
                (const __attribute__((address_space(1))) unsigned int*)(csrc + (size_t)u * 8),
                (__attribute__((address_space(3))) unsigned int*)(BKV + u * 16), 16, 0, 0);
        }
        __syncthreads();

        f32x4 accp[4] = {};
        #pragma unroll
        for (int ks = 0; ks < 2; ++ks) {
            #pragma unroll
            for (int ff = 0; ff < 4; ++ff) {
                int f = ff * 16 + li;
                short8 ah = *(const short8*)(BP +        (ks * 4 + lg) * 1024 + f * 16);
                short8 al = *(const short8*)(BP + 8192 + (ks * 4 + lg) * 1024 + f * 16);
                accp[ff] = __builtin_amdgcn_mfma_f32_16x16x32_bf16(ah, qh[ks], accp[ff], 0, 0, 0);
                accp[ff] = __builtin_amdgcn_mfma_f32_16x16x32_bf16(ah, ql[ks], accp[ff], 0, 0, 0);
                accp[ff] = __builtin_amdgcn_mfma_f32_16x16x32_bf16(al, qh[ks], accp[ff], 0, 0, 0);
            }
        }

        #pragma unroll
        for (int ff = 0; ff < 4; ++ff) {
            float4 ks4 = *(const float4*)&ksum[(size_t)bh * 256 + fc * 64 + ff * 16 + lg * 4];
            float kse[4] = {ks4.x, ks4.y, ks4.z, ks4.w};
            us4 h4, l4;
            #pragma unroll
            for (int r = 0; r < 4; ++r) {
                float v = elu1f(accp[ff][r]);
                zacc += v * kse[r];
                unsigned short hv = f2bf(v);
                h4[r] = hv;
                l4[r] = f2bf(v - bf2f(hv));
            }
            int boff = (ff * 2 + (lg >> 1)) * 1024 + (w * 16 + li) * 16 + (lg & 1) * 8;
            *(us4*)(QP + boff) = h4;
            *(us4*)(QP + 8192 + boff) = l4;
        }
        __syncthreads();

        #pragma unroll
        for (int ks = 0; ks < 2; ++ks) {
            short8 a2h = *(const short8*)(QP +        (ks * 4 + lg) * 1024 + (w * 16 + li) * 16);
            short8 a2l = *(const short8*)(QP + 8192 + (ks * 4 + lg) * 1024 + (w * 16 + li) * 16);
            #pragma unroll
            for (int fd = 0; fd < 4; ++fd) {
                int d = fd * 16 + li;
                short8 b2h = *(const short8*)(BKV +        (ks * 4 + lg) * 1024 + d * 16);
                short8 b2l = *(const short8*)(BKV + 8192 + (ks * 4 + lg) * 1024 + d * 16);
                attnacc[fd] = __builtin_amdgcn_mfma_f32_16x16x32_bf16(a2h, b2h, attnacc[fd], 0, 0, 0);
                attnacc[fd] = __builtin_amdgcn_mfma_f32_16x16x32_bf16(a2h, b2l, attnacc[fd], 0, 0, 0);
                attnacc[fd] = __builtin_amdgcn_mfma_f32_16x16x32_bf16(a2l, b2h, attnacc[fd], 0, 0, 0);
            }
        }
        __syncthreads();
    }

    zacc += __shfl_xor(zacc, 16, 64);
    zacc += __shfl_xor(zacc, 32, 64);
    float zn = 1.0f / (zacc + 1e-8f);
    float zr[4];
    #pragma unroll
    for (int r = 0; r < 4; ++r) zr[r] = __shfl(zn, lg * 4 + r, 64);

    float* Sb = (float*)smem;
    #pragma unroll
    for (int fd = 0; fd < 4; ++fd) {
        int d = fd * 16 + li;
        #pragma unroll
        for (int r = 0; r < 4; ++r) {
            int n = w * 16 + lg * 4 + r;
            Sb[n * 68 + d] = attnacc[fd][r] * zr[r];
        }
    }
    __syncthreads();

    const int mt = nt >> 1, rhalf = (nt & 1) * 64;
    #pragma unroll
    for (int i = 0; i < 2; ++i) {
        int u = tid + i * 256;
        int r64 = u >> 3, c8 = u & 7;
        int ktL = c8 >> 2, kg = c8 & 3;
        const float* sp = Sb + r64 * 68 + ktL * 32 + kg * 8;
        float f[8];
        #pragma unroll
        for (int j = 0; j < 8; ++j) f[j] = sp[j];
        uint4 ph, pl;
        pack8(f, ph, pl);
        size_t t = (size_t)mt * 32 + (h * 2 + ktL);
        unsigned short* dst = attnpre + t * 8192 + (size_t)(kg * 128 + rhalf + r64) * 8;
        *(uint4*)dst = ph;
        *(uint4*)(dst + 4096) = pl;
    }
}

// ---------------------------------------------------------------------------
extern "C" void kernel_launch(void* const* d_in, const int* in_sizes, int n_in,
                              void* d_out, int out_size, void* d_ws, size_t ws_size,
                              hipStream_t stream)
{
    const float* x      = (const float*)d_in[0];
    const float* w_qkv  = (const float*)d_in[1];
    const float* proj   = (const float*)d_in[2];
    const float* w_out  = (const float*)d_in[3];
    const float* b_out  = (const float*)d_in[4];
    float* out = (float*)d_out;
    float* ws  = (float*)d_ws;

    if (ws_size < (size_t)WS_FLOATS * sizeof(float)) return;

    unsigned short* proj_pre = (unsigned short*)(ws + OFF_PROJPRE);
    unsigned short* kv_pre   = (unsigned short*)(ws + OFF_KVPRE);
    float* ksum  = ws + OFF_KSUM;
    float* kvst  = ws + OFF_KVST;
    unsigned short* wkv_pre  = (unsigned short*)(ws + OFF_WKV);
    unsigned short* wq_pre   = (unsigned short*)(ws + OFF_WQ);
    unsigned short* wout_pre = (unsigned short*)(ws + OFF_WOUT);
    unsigned short* xpre     = (unsigned short*)(ws + OFF_XPRE);
    float* kvbuf = ws + OFF_KVBUF;
    float* qbuf  = ws + OFF_QBUF;
    unsigned short* attnpre  = (unsigned short*)(ws + OFF_ATTNPRE);

    dim3 blk(256);
    zero_kernel<<<1024, blk, 0, stream>>>((float4*)(ws + OFF_KSUM), ZERO_F4);
    preconv_kernel<<<512, blk, 0, stream>>>(w_qkv, H3, 1024, 16, wkv_pre);
    preconv_kernel<<<256, blk, 0, stream>>>(w_qkv, H3, 0, 8, wq_pre);
    preconv_kernel<<<256, blk, 0, stream>>>(w_out, DIM, 0, 8, wout_pre);
    projconv_kernel<<<64, blk, 0, stream>>>(proj, proj_pre);

    for (int b = 0; b < NB; ++b) {
        const float* xb = x + (size_t)b * NTOK * DIM;
        aconv_kernel<<<1024, blk, 0, stream>>>(xb, xpre);
        mfma_gemm_pre<<<dim3(16, 32), blk, 0, stream>>>(
            xpre, wkv_pre, nullptr, kvbuf, 1024, 2048, 16, 0);
        kv_mfma<<<dim3(32, 16), blk, 0, stream>>>(kvbuf, proj_pre, kvst, ksum, b);
        kvconv_kernel<<<64, blk, 0, stream>>>(kvst, kv_pre, b);
        mfma_gemm_pre<<<dim3(8, 32), blk, 0, stream>>>(
            xpre, wq_pre, nullptr, qbuf, 1024, 1024, 8, 0);
        attn_mfma<<<dim3(64, 16), blk, 0, stream>>>(
            qbuf, proj_pre, kv_pre, ksum, attnpre, b);
        mfma_gemm_pre<<<dim3(8, 32), blk, 0, stream>>>(
            attnpre, wout_pre, b_out, out + (size_t)b * NTOK * DIM, 1024, 1024, 8, 1);
    }
}